// Round 8
// baseline (467.153 us; speedup 1.0000x reference)
//
#include <hip/hip_runtime.h>

#define C 512
#define HW 4096
#define EPSV 1e-5f

typedef _Float16 fp16x8 __attribute__((ext_vector_type(8)));
typedef _Float16 fp16x4 __attribute__((ext_vector_type(4)));
typedef float f32x4 __attribute__((ext_vector_type(4)));

// ---- workspace layout (bytes) ----
#define OFF_MC    (0)
#define OFF_RC    (8192)
#define OFF_MS    (16384)
#define OFF_RS    (24576)
#define OFF_BETAF (32768)
#define OFF_V     (40960)
#define OFF_BZ    (49152)
#define OFF_T     (65536)                      // t[b][m] f32, 64 KB
#define OFF_SP    (131072)                     // stats partials (2MB); reused as As f16 after finalize
#define OFF_A     (OFF_SP + 2097152)           // 1 MB (A f32)
#define OFF_WZ    (OFF_A + 1048576)            // 1 MB (Wz f16 FT, 512KB used)
#define OFF_XCT   (OFF_WZ + 1048576)           // 16 MB (fragment-tiled; reused as Scl after qk)
#define OFF_XST   (OFF_XCT + 16777216)         // 16 MB (fragment-tiled)
#define OFF_KT    (OFF_XST + 16777216)         // 16 MB (fragment-tiled)
#define OFF_HM    (OFF_KT + 16777216)          // 16 MB (fragment-tiled Hp layout)
#define OFF_ML    (OFF_HM + 16777216)          // float2[4][4096][64] = 8 MB
#define OFF_S     (OFF_ML + 8388608)           // f16 [4] fragment-tiled [4096][4096] = 128 MB
// total ~= 204 MB

// Fragment-tiled layout for transposed f16 tensors (xcT, xsT, Kt) and 512x512
// operands (As, Wz): elem (row n, col c) ->
//   ((n>>4)*16 + (c>>5))*512 + ((c>>3)&3)*128 + (n&15)*8 + (c&7)
#define FT_IDX(n, c) ((((size_t)((n) >> 4) * 16 + ((c) >> 5)) * 512) + \
                      ((((c) >> 3) & 3) * 128) + (((n) & 15) * 8) + ((c) & 7))

// S fragment-tiled (per batch, n,m in [0,4096)):
#define SFT_IDX(n, m) ((((size_t)((n) >> 4) * 128 + ((m) >> 5)) * 512) + \
                       ((((m) >> 3) & 3) * 128) + (((n) & 15) * 8) + ((m) & 7))

// Hp tiled layout (per batch b): (co, m) at ((co>>4)*512 + (m>>3))*128 + (co&15)*8 + (m&7)

// ---------------------------------------------------------------------------
// 1) fused transpose + f16 cast + partial stats. COALESCED fp32 reads.
// ---------------------------------------------------------------------------
__global__ void transpose_stats_kernel(const float* __restrict__ xc, const float* __restrict__ xs,
                                       char* __restrict__ ws)
{
    int bx = blockIdx.x;                  // 4096 = 2 * 4 * 8 * 64
    int tensor = bx >> 11, b = (bx >> 9) & 3, c0 = ((bx >> 6) & 7) * 64, n0 = (bx & 63) * 64;
    const float* src = tensor ? xs : xc;
    _Float16* dst = (_Float16*)(ws + (tensor ? OFF_XST : OFF_XCT));
    float2* part = (float2*)(ws + OFF_SP);

    __shared__ _Float16 tile[64][72];
    __shared__ float sredL[64], ssredL[64];

    int tid = threadIdx.x, w = tid >> 6, lane = tid & 63, cq = lane >> 4, l16 = lane & 15;
    #pragma unroll
    for (int k = 0; k < 4; k++) {
        int cr = w * 16 + k * 4 + cq;                 // c offset within tile
        int nf = l16 * 4;                             // n offset within tile
        float4 v = *(const float4*)(src + ((size_t)(b * C + c0 + cr)) * HW + n0 + nf);
        float s = v.x + v.y + v.z + v.w;
        float ss = v.x * v.x + v.y * v.y + v.z * v.z + v.w * v.w;
        s += __shfl_xor(s, 1); ss += __shfl_xor(ss, 1);
        s += __shfl_xor(s, 2); ss += __shfl_xor(ss, 2);
        s += __shfl_xor(s, 4); ss += __shfl_xor(ss, 4);
        s += __shfl_xor(s, 8); ss += __shfl_xor(ss, 8);
        if (l16 == 0) { sredL[cr] = s; ssredL[cr] = ss; }
        tile[nf][cr] = (_Float16)v.x; tile[nf + 1][cr] = (_Float16)v.y;
        tile[nf + 2][cr] = (_Float16)v.z; tile[nf + 3][cr] = (_Float16)v.w;
    }
    __syncthreads();
    if (tid < 64) {
        part[((size_t)((tensor * 4 + b) * 512 + c0 + tid)) * 64 + (n0 >> 6)] =
            make_float2(sredL[tid], ssredL[tid]);
    }
    _Float16* dstB = dst + (size_t)b * HW * C;
    #pragma unroll
    for (int i = 0; i < 2; i++) {
        int g = tid + i * 256, row = g >> 3, c8 = (g & 7) * 8;
        int n = n0 + row, c = c0 + c8;
        *(fp16x8*)&dstB[FT_IDX(n, c)] = *(const fp16x8*)&tile[row][c8];
    }
}

// ---------------------------------------------------------------------------
// 1b) finalize stats
// ---------------------------------------------------------------------------
__global__ void finalize_stats_kernel(char* __restrict__ ws)
{
    int ch = blockIdx.x * 256 + threadIdx.x;       // 16 blocks -> 4096 channels
    const float2* part = (const float2*)(ws + OFF_SP) + (size_t)ch * 64;
    float S = 0.f, SS = 0.f;
    for (int k = 0; k < 64; k++) { float2 v = part[k]; S += v.x; SS += v.y; }
    int tensor = ch >> 11, rem = ch & 2047;
    float m = S / (float)HW;
    float var = (SS - S * m) / (float)(HW - 1) + EPSV;   // unbiased (n-1) + EPS
    ((float*)(ws + (tensor ? OFF_MS : OFF_MC)))[rem] = m;
    ((float*)(ws + (tensor ? OFF_RS : OFF_RC)))[rem] = rsqrtf(var);
}

// ---------------------------------------------------------------------------
// 2) small precomputes: A = Wf^T Wg (f32), Wz = Wo Wh (f16 FT!), betaf, bz
// ---------------------------------------------------------------------------
__global__ void precompute_kernel(const float* __restrict__ Wf, const float* __restrict__ Wg,
                                  const float* __restrict__ Wo, const float* __restrict__ Wh,
                                  const float* __restrict__ bf, const float* __restrict__ bh,
                                  char* __restrict__ ws)
{
    float* A = (float*)(ws + OFF_A);
    _Float16* Wz16 = (_Float16*)(ws + OFF_WZ);
    float* betaf = (float*)(ws + OFF_BETAF);
    float* bz = (float*)(ws + OFF_BZ);
    const float* mc = (const float*)(ws + OFF_MC);
    const float* rc = (const float*)(ws + OFF_RC);
    int bx = blockIdx.x, t = threadIdx.x;
    if (bx < 512) {                              // A or Wz, 2 output rows per block
        bool isA = bx < 256;
        int r0 = (isA ? bx : bx - 256) * 2;
        float a00 = 0.f, a01 = 0.f, a10 = 0.f, a11 = 0.f;
        for (int k = 0; k < C; k++) {
            float r0v, r1v, c0v, c1v;
            if (isA) {                           // A[i][j] = sum_co Wf[co][i]*Wg[co][j]
                r0v = Wf[k * C + r0]; r1v = Wf[k * C + r0 + 1];
                c0v = Wg[k * C + t];  c1v = Wg[k * C + t + 256];
            } else {                             // Wz[o][j] = sum_i Wo[o][i]*Wh[i][j]
                r0v = Wo[r0 * C + k]; r1v = Wo[(r0 + 1) * C + k];
                c0v = Wh[k * C + t];  c1v = Wh[k * C + t + 256];
            }
            a00 += r0v * c0v; a01 += r0v * c1v;
            a10 += r1v * c0v; a11 += r1v * c1v;
        }
        if (isA) {
            A[r0 * C + t] = a00;       A[r0 * C + t + 256] = a01;
            A[(r0 + 1) * C + t] = a10; A[(r0 + 1) * C + t + 256] = a11;
        } else {
            Wz16[FT_IDX(r0, t)] = (_Float16)a00;
            Wz16[FT_IDX(r0, t + 256)] = (_Float16)a01;
            Wz16[FT_IDX(r0 + 1, t)] = (_Float16)a10;
            Wz16[FT_IDX(r0 + 1, t + 256)] = (_Float16)a11;
        }
    } else if (bx < 520) {                       // betaf[b][co] = bf[co] - sum_i Wf[co][i]*mc*rc
        int g = (bx - 512) * 256 + t, b = g >> 9, co = g & 511;
        float acc = 0.f;
        for (int i = 0; i < C; i++) acc += Wf[co * C + i] * mc[b * C + i] * rc[b * C + i];
        betaf[g] = bf[co] - acc;
    } else {                                     // bz[co] = sum_i Wo[co][i]*bh[i]
        int co = (bx - 520) * 256 + t;
        float acc = 0.f;
        for (int i = 0; i < C; i++) acc += Wo[co * C + i] * bh[i];
        bz[co] = acc;
    }
}

// ---------------------------------------------------------------------------
// 2b) As[b] = diag(rc_b) * A * diag(rs_b), f16 FT layout (into dead SP buf).
// ---------------------------------------------------------------------------
__global__ void scaleA_kernel(char* __restrict__ ws)
{
    const float* __restrict__ A = (const float*)(ws + OFF_A);
    const float* __restrict__ rc = (const float*)(ws + OFF_RC);
    const float* __restrict__ rs = (const float*)(ws + OFF_RS);
    _Float16* __restrict__ As = (_Float16*)(ws + OFF_SP);

    int gid = blockIdx.x * 256 + threadIdx.x;   // 131072 = 4b * 512 sub * 64
    int b = gid >> 15, rem = gid & 32767;
    int sub = rem >> 6, low6 = rem & 63;
    int r16 = sub >> 4, cb4 = sub & 15;
    int q = low6 >> 4, l16 = low6 & 15;
    int r = r16 * 16 + l16, j0 = (cb4 * 4 + q) * 8;

    float4 a0 = *(const float4*)&A[r * C + j0];
    float4 a1 = *(const float4*)&A[r * C + j0 + 4];
    float4 s0 = *(const float4*)&rs[b * C + j0];
    float4 s1 = *(const float4*)&rs[b * C + j0 + 4];
    float rcv = rc[b * C + r];
    fp16x8 o;
    o[0] = (_Float16)(a0.x * rcv * s0.x); o[1] = (_Float16)(a0.y * rcv * s0.y);
    o[2] = (_Float16)(a0.z * rcv * s0.z); o[3] = (_Float16)(a0.w * rcv * s0.w);
    o[4] = (_Float16)(a1.x * rcv * s1.x); o[5] = (_Float16)(a1.y * rcv * s1.y);
    o[6] = (_Float16)(a1.z * rcv * s1.z); o[7] = (_Float16)(a1.w * rcv * s1.w);
    *(fp16x8*)&As[(size_t)b * 262144 + (size_t)sub * 512 + low6 * 8] = o;
}

// v[b][j] = rs[b][j] * sum_co betaf[b][co]*Wg[co][j]
__global__ void precompute_v_kernel(const float* __restrict__ Wg, char* __restrict__ ws)
{
    const float* betaf = (const float*)(ws + OFF_BETAF);
    const float* rs = (const float*)(ws + OFF_RS);
    float* v = (float*)(ws + OFF_V);
    int g = blockIdx.x * 32 + (threadIdx.x >> 3);   // 0..2047 output index
    int b = g >> 9, j = g & 511, cq = threadIdx.x & 7;
    float acc = 0.f;
    for (int co = cq * 64; co < cq * 64 + 64; co++) acc += betaf[b * C + co] * Wg[co * C + j];
    acc += __shfl_xor(acc, 1);
    acc += __shfl_xor(acc, 2);
    acc += __shfl_xor(acc, 4);
    if (cq == 0) v[g] = rs[b * C + j] * acc;
}

// ---------------------------------------------------------------------------
// 3) fused prep GEMM -> Kt (f16 FT) and Hp (f16 tiled). All loads wave-linear.
// ---------------------------------------------------------------------------
__global__ void __launch_bounds__(256) prep_gemm_kernel(char* __restrict__ ws)
{
    const _Float16* __restrict__ As = (const _Float16*)(ws + OFF_SP);
    const _Float16* __restrict__ Wz16 = (const _Float16*)(ws + OFF_WZ);
    const float* __restrict__ bz = (const float*)(ws + OFF_BZ);
    const _Float16* __restrict__ xsT = (const _Float16*)(ws + OFF_XST);
    _Float16* __restrict__ Kt = (_Float16*)(ws + OFF_KT);
    _Float16* __restrict__ Hp = (_Float16*)(ws + OFF_HM);

    int bx = blockIdx.x;                 // 1024 = 4b * 8 rowblk * 32 mblk
    int b = bx & 3, rest = bx >> 2;
    int r128 = rest >> 5, mb = rest & 31;
    int r0 = r128 * 128, m0 = mb * 128;
    int w = threadIdx.x >> 6, lane = threadIdx.x & 63, q = lane >> 4, l16 = lane & 15;
    int wr = (w & 1) * 64, wm = (w >> 1) * 64;
    bool isK = (r0 < 512);
    int rbase = (isK ? r0 : r0 - 512) + wr;

    f32x4 zz = {0.f, 0.f, 0.f, 0.f};
    f32x4 acc[4][4];
    #pragma unroll
    for (int rt = 0; rt < 4; rt++)
        #pragma unroll
        for (int mt = 0; mt < 4; mt++) acc[rt][mt] = zz;

    const _Float16* ap = (isK ? As + (size_t)b * 262144 : Wz16)
                         + (size_t)(rbase >> 4) * 8192 + q * 128 + l16 * 8;
    const _Float16* xb = xsT + (size_t)b * HW * C
                             + (size_t)((m0 + wm) >> 4) * 8192 + q * 128 + l16 * 8;

    for (int ks = 0; ks < 16; ks++) {
        fp16x8 afr[4], bfr[4];
        #pragma unroll
        for (int rt = 0; rt < 4; rt++)
            afr[rt] = *(const fp16x8*)(ap + (size_t)rt * 8192 + ks * 512);
        #pragma unroll
        for (int mt = 0; mt < 4; mt++)
            bfr[mt] = *(const fp16x8*)(xb + (size_t)(mt * 16 + ks) * 512);
        #pragma unroll
        for (int rt = 0; rt < 4; rt++)
            #pragma unroll
            for (int mt = 0; mt < 4; mt++)
                acc[rt][mt] = __builtin_amdgcn_mfma_f32_16x16x32_f16(afr[rt], bfr[mt], acc[rt][mt], 0, 0, 0);
    }

    if (isK) {
        _Float16* KtB = Kt + (size_t)b * HW * C;
        #pragma unroll
        for (int rt = 0; rt < 4; rt++)
            #pragma unroll
            for (int mt = 0; mt < 4; mt++) {
                int m = m0 + wm + mt * 16 + l16;
                int cb = r0 + wr + rt * 16 + q * 4;
                fp16x4 h;
                h[0] = (_Float16)acc[rt][mt][0]; h[1] = (_Float16)acc[rt][mt][1];
                h[2] = (_Float16)acc[rt][mt][2]; h[3] = (_Float16)acc[rt][mt][3];
                *(fp16x4*)&KtB[FT_IDX(m, cb)] = h;
            }
    } else {
        _Float16* HpB = Hp + (size_t)b * 2097152;
        #pragma unroll
        for (int rt = 0; rt < 4; rt++) {
            float bzv[4];
            #pragma unroll
            for (int reg = 0; reg < 4; reg++) bzv[reg] = bz[rbase + rt * 16 + q * 4 + reg];
            #pragma unroll
            for (int mt = 0; mt < 4; mt++) {
                int m = m0 + wm + mt * 16 + l16;
                int mbase = (m >> 3) * 128 + (m & 7);
                #pragma unroll
                for (int reg = 0; reg < 4; reg++) {
                    int co = rbase + rt * 16 + q * 4 + reg;
                    HpB[(size_t)(co >> 4) * 65536 + mbase + (co & 15) * 8] =
                        (_Float16)(acc[rt][mt][reg] + bzv[reg]);
                }
            }
        }
    }
}

// ---------------------------------------------------------------------------
// 4) t[b][m] = sum_j v[b][j] * xsT[b][m][j] — wave-linear FT loads.
// ---------------------------------------------------------------------------
__global__ void t_kernel(char* __restrict__ ws)
{
    const float* v = (const float*)(ws + OFF_V);
    const _Float16* __restrict__ xsT = (const _Float16*)(ws + OFF_XST);
    float* tG = (float*)(ws + OFF_T);
    int bx = blockIdx.x;                      // 256 = 4 b * 64 mblk(64m)
    int b = bx >> 6, mb = bx & 63;
    int tid = threadIdx.x, w = tid >> 6, lane = tid & 63, q = lane >> 4, l16 = lane & 15;
    int M16 = mb * 4 + w;                     // m-subtile; m = M16*16 + l16
    const _Float16* p = xsT + (size_t)b * HW * C + (size_t)M16 * 8192 + q * 128 + l16 * 8;
    const float* vp = v + b * C + q * 8;
    float acc = 0.f;
    #pragma unroll
    for (int st = 0; st < 16; st++) {
        fp16x8 xv = *(const fp16x8*)(p + st * 512);
        float4 v0 = *(const float4*)(vp + st * 32);
        float4 v1 = *(const float4*)(vp + st * 32 + 4);
        acc += (float)xv[0] * v0.x + (float)xv[1] * v0.y + (float)xv[2] * v0.z + (float)xv[3] * v0.w
             + (float)xv[4] * v1.x + (float)xv[5] * v1.y + (float)xv[6] * v1.z + (float)xv[7] * v1.w;
    }
    acc += __shfl_xor(acc, 16);
    acc += __shfl_xor(acc, 32);
    if (q == 0) tG[b * HW + M16 * 16 + l16] = acc;
}

// ---------------------------------------------------------------------------
// 5) pass A: S-tile = Q @ Kt^T, BIG TILE 128n x 256m (K=512) + t[m].
//    Per wave: 64n x 128m, acc[4][8] (128 VGPR), 32 MFMA : 12 loads per
//    K-step (was 16:8) -> less addr-VALU per MFMA. Per-(row, 64-m-tile)
//    max/sumexp unchanged (mt groups of 4 = the same 64-m tiles); stores
//    p = exp(s-tilemax) f16 to S via two 64-m LDS transpose passes.
// ---------------------------------------------------------------------------
__global__ void __launch_bounds__(256, 2) qk_kernel(char* __restrict__ ws)
{
    const _Float16* __restrict__ xcT = (const _Float16*)(ws + OFF_XCT);
    const _Float16* __restrict__ Kt = (const _Float16*)(ws + OFF_KT);
    const float* __restrict__ tG = (const float*)(ws + OFF_T);
    float2* __restrict__ ML = (float2*)(ws + OFF_ML);
    _Float16* __restrict__ Sg = (_Float16*)(ws + OFF_S);

    int bx = blockIdx.x;                  // 2048: low3 = (b<<1)|mh (XCD spread)
    int b = (bx >> 1) & 3, mh = bx & 1;
    int rest = bx >> 3, mlo = rest & 7, ntile = rest >> 3;   // mlo 0..7, ntile 0..31
    int m0 = (mh * 8 + mlo) * 256, n0 = ntile * 128;
    int tid = threadIdx.x, w = tid >> 6, lane = tid & 63, q = lane >> 4, l16 = lane & 15;
    int wn = (w & 1) * 64, wm = (w >> 1) * 128;

    const _Float16* ab = xcT + (size_t)b * HW * C
                             + (size_t)((n0 + wn) >> 4) * 8192 + q * 128 + l16 * 8;
    const _Float16* bb = Kt + (size_t)b * HW * C
                            + (size_t)((m0 + wm) >> 4) * 8192 + q * 128 + l16 * 8;

    f32x4 zz = {0.f, 0.f, 0.f, 0.f};
    f32x4 acc[4][8];
    #pragma unroll
    for (int nt = 0; nt < 4; nt++)
        #pragma unroll
        for (int mt = 0; mt < 8; mt++) acc[nt][mt] = zz;

    #pragma unroll 2
    for (int ks = 0; ks < 16; ks++) {
        fp16x8 afr[4], bfr[8];
        #pragma unroll
        for (int nt = 0; nt < 4; nt++)
            afr[nt] = *(const fp16x8*)(ab + (size_t)(nt * 16 + ks) * 512);
        #pragma unroll
        for (int mt = 0; mt < 8; mt++)
            bfr[mt] = *(const fp16x8*)(bb + (size_t)(mt * 16 + ks) * 512);
        #pragma unroll
        for (int nt = 0; nt < 4; nt++)
            #pragma unroll
            for (int mt = 0; mt < 8; mt++)
                acc[nt][mt] = __builtin_amdgcn_mfma_f32_16x16x32_f16(afr[nt], bfr[mt], acc[nt][mt], 0, 0, 0);
    }

    // ---- epilogue: + t[m], per-row 64-m-tile max / exp / sum (2 tiles) ----
    {
        float tv[8];
        #pragma unroll
        for (int mt = 0; mt < 8; mt++) tv[mt] = tG[b * HW + m0 + wm + mt * 16 + l16];
        #pragma unroll
        for (int nt = 0; nt < 4; nt++)
            #pragma unroll
            for (int mt = 0; mt < 8; mt++)
                #pragma unroll
                for (int reg = 0; reg < 4; reg++) acc[nt][mt][reg] += tv[mt];
    }

    __shared__ _Float16 Pl[4][64][72];
    _Float16* SgB = Sg + (size_t)b * 16777216;
    int tlb = (m0 + wm) >> 6;

    #pragma unroll
    for (int g = 0; g < 2; g++) {
        float rm[4][4], sum[4][4];
        #pragma unroll
        for (int nt = 0; nt < 4; nt++)
            #pragma unroll
            for (int reg = 0; reg < 4; reg++)
                rm[nt][reg] = fmaxf(fmaxf(acc[nt][g * 4][reg], acc[nt][g * 4 + 1][reg]),
                                    fmaxf(acc[nt][g * 4 + 2][reg], acc[nt][g * 4 + 3][reg]));
        #pragma unroll
        for (int s = 1; s < 16; s <<= 1)
            #pragma unroll
            for (int nt = 0; nt < 4; nt++)
                #pragma unroll
                for (int reg = 0; reg < 4; reg++)
                    rm[nt][reg] = fmaxf(rm[nt][reg], __shfl_xor(rm[nt][reg], s));
        #pragma unroll
        for (int nt = 0; nt < 4; nt++)
            #pragma unroll
            for (int reg = 0; reg < 4; reg++) sum[nt][reg] = 0.f;
        #pragma unroll
        for (int nt = 0; nt < 4; nt++)
            #pragma unroll
            for (int mt = 0; mt < 4; mt++)
                #pragma unroll
                for (int reg = 0; reg < 4; reg++) {
                    float pv = __expf(acc[nt][g * 4 + mt][reg] - rm[nt][reg]);
                    acc[nt][g * 4 + mt][reg] = pv;
                    sum[nt][reg] += pv;
                }
        #pragma unroll
        for (int s = 1; s < 16; s <<= 1)
            #pragma unroll
            for (int nt = 0; nt < 4; nt++)
                #pragma unroll
                for (int reg = 0; reg < 4; reg++)
                    sum[nt][reg] += __shfl_xor(sum[nt][reg], s);

        if (l16 == 0) {
            #pragma unroll
            for (int nt = 0; nt < 4; nt++)
                #pragma unroll
                for (int reg = 0; reg < 4; reg++)
                    ML[((size_t)(b * HW + n0 + wn + nt * 16 + q * 4 + reg)) * 64 + tlb + g] =
                        make_float2(rm[nt][reg], sum[nt][reg]);
        }

        // f16 + LDS transpose-spill for this 64-m half, then 16B stores
        #pragma unroll
        for (int nt = 0; nt < 4; nt++)
            #pragma unroll
            for (int mt = 0; mt < 4; mt++)
                #pragma unroll
                for (int reg = 0; reg < 4; reg++)
                    Pl[w][nt * 16 + q * 4 + reg][mt * 16 + l16] =
                        (_Float16)acc[nt][g * 4 + mt][reg];
        __syncthreads();
        #pragma unroll
        for (int i = 0; i < 8; i++) {
            int row = i * 8 + (lane >> 3), c8 = (lane & 7) * 8;
            int n = n0 + wn + row, m = m0 + wm + g * 64 + c8;
            *(fp16x8*)&SgB[SFT_IDX(n, m)] = *(const fp16x8*)&Pl[w][row][c8];
        }
        __syncthreads();
    }
}

// ---------------------------------------------------------------------------
// 5b) per-row global softmax scales: Scl[b][tile][n] = e^(m_tile - M)/L (f32)
// ---------------------------------------------------------------------------
__global__ void __launch_bounds__(256) scale_kernel(char* __restrict__ ws)
{
    const float* __restrict__ mlf0 = (const float*)(ws + OFF_ML);
    float* __restrict__ Scl = (float*)(ws + OFF_XCT);
    __shared__ float mlv[64][129];       // [row][2*tile + {0:max,1:sum}]
    __shared__ float Ms[64], Li[64];

    int g0 = blockIdx.x * 64;            // global row base (b*4096 + n), 16384 total
    int tid = threadIdx.x;
    const float* mlf = mlf0 + (size_t)g0 * 128;   // 64 rows x 128 f32 (float2[64])

    #pragma unroll
    for (int i = 0; i < 8; i++) {
        int f4 = i * 256 + tid;          // 2048 float4 = 64 rows x 32
        int row = f4 >> 5, c4 = (f4 & 31) * 4;
        float4 v = *(const float4*)(mlf + row * 128 + c4);
        mlv[row][c4] = v.x; mlv[row][c4 + 1] = v.y;
        mlv[row][c4 + 2] = v.z; mlv[row][c4 + 3] = v.w;
    }
    __syncthreads();
    if (tid < 64) {
        float M = -1e30f;
        #pragma unroll
        for (int k = 0; k < 64; k++) M = fmaxf(M, mlv[tid][k * 2]);
        float L = 0.f;
        #pragma unroll
        for (int k = 0; k < 64; k++) L += mlv[tid][k * 2 + 1] * __expf(mlv[tid][k * 2] - M);
        Ms[tid] = M; Li[tid] = 1.f / L;
    }
    __syncthreads();
    int b = g0 >> 12, nbase = g0 & 4095;
    float* sp = Scl + (size_t)b * 262144 + nbase;
    int row = tid & 63, tsub = tid >> 6;
    #pragma unroll
    for (int pass = 0; pass < 16; pass++) {
        int tile = pass * 4 + tsub;
        sp[(size_t)tile * 4096 + row] = __expf(mlv[row][tile * 2] - Ms[row]) * Li[row];
    }
}

// ---------------------------------------------------------------------------
// 6) pass C: O = (p * scale) @ Hp^T — LDS-Hp pipeline (unchanged from r6).
// ---------------------------------------------------------------------------
__global__ void __launch_bounds__(256, 4) pv_kernel(const float* __restrict__ xc,
                                                    const float* __restrict__ bo,
                                                    float* __restrict__ out,
                                                    char* __restrict__ ws)
{
    const _Float16* __restrict__ Sft = (const _Float16*)(ws + OFF_S);
    const _Float16* __restrict__ Hp = (const _Float16*)(ws + OFF_HM);
    const float* __restrict__ Scl = (const float*)(ws + OFF_XCT);

    int bx = blockIdx.x;                 // 1024 = 32 ntb * 8 cog * 4 b
    int b = bx & 3, cog = (bx >> 2) & 7, ntb = bx >> 5;
    int co0 = cog * 64;
    int tid = threadIdx.x, w = tid >> 6, lane = tid & 63, q = lane >> 4, l16 = lane & 15;
    int n0w = ntb * 128 + w * 32;

    __shared__ _Float16 Hl[2][4096];     // 8KB chunk slice (64co x 64keys), dbuf

    int ln64 = lane;
    const _Float16* hsrc = Hp + (size_t)b * 2097152
                              + (size_t)((co0 >> 4) + w) * 65536 + ln64 * 8;
    const _Float16* sb = Sft + (size_t)b * 16777216
                             + (size_t)(ntb * 8 + w * 2) * 65536 + q * 128 + l16 * 8;
    const float* sc = Scl + (size_t)b * 262144 + n0w + q * 4;

    // prologue: stage chunk 0
    {
        fp16x8 s0 = *(const fp16x8*)(hsrc);
        fp16x8 s1 = *(const fp16x8*)(hsrc + 512);
        *(fp16x8*)&Hl[0][w * 1024 + ln64 * 8] = s0;
        *(fp16x8*)&Hl[0][w * 1024 + 512 + ln64 * 8] = s1;
    }
    __syncthreads();

    f32x4 zz = {0.f, 0.f, 0.f, 0.f};
    f32x4 acc[2][4];
    #pragma unroll
    for (int nt = 0; nt < 2; nt++)
        #pragma unroll
        for (int ct = 0; ct < 4; ct++) acc[nt][ct] = zz;

    for (int chunk = 0; chunk < 64; chunk++) {
        int buf = chunk & 1;
        fp16x8 s0n, s1n;
        if (chunk < 63) {
            s0n = *(const fp16x8*)(hsrc + (chunk + 1) * 1024);
            s1n = *(const fp16x8*)(hsrc + (chunk + 1) * 1024 + 512);
        }

        f32x4 tmp[2][4];
        #pragma unroll
        for (int km = 0; km < 2; km++) {
            fp16x8 afr[2], bfr[4];
            #pragma unroll
            for (int nt = 0; nt < 2; nt++)
                afr[nt] = *(const fp16x8*)(sb + (size_t)nt * 65536 + (chunk * 2 + km) * 512);
            #pragma unroll
            for (int ct = 0; ct < 4; ct++)
                bfr[ct] = *(const fp16x8*)&Hl[buf][ct * 1024 + (km * 4 + q) * 128 + l16 * 8];
            #pragma unroll
            for (int nt = 0; nt < 2; nt++)
                #pragma unroll
                for (int ct = 0; ct < 4; ct++)
                    tmp[nt][ct] = __builtin_amdgcn_mfma_f32_16x16x32_f16(
                        afr[nt], bfr[ct], km == 0 ? zz : tmp[nt][ct], 0, 0, 0);
        }
        float4 sv0 = *(const float4*)(sc + chunk * 4096);
        float4 sv1 = *(const float4*)(sc + chunk * 4096 + 16);
        float sva[2][4] = {{sv0.x, sv0.y, sv0.z, sv0.w}, {sv1.x, sv1.y, sv1.z, sv1.w}};
        #pragma unroll
        for (int nt = 0; nt < 2; nt++)
            #pragma unroll
            for (int ct = 0; ct < 4; ct++)
                #pragma unroll
                for (int reg = 0; reg < 4; reg++)
                    acc[nt][ct][reg] += tmp[nt][ct][reg] * sva[nt][reg];

        if (chunk < 63) {
            *(fp16x8*)&Hl[buf ^ 1][w * 1024 + ln64 * 8] = s0n;
            *(fp16x8*)&Hl[buf ^ 1][w * 1024 + 512 + ln64 * 8] = s1n;
        }
        __syncthreads();
    }

    // ---- epilogue: + bo + content ----
    #pragma unroll
    for (int nt = 0; nt < 2; nt++)
        #pragma unroll
        for (int ct = 0; ct < 4; ct++) {
            int co = co0 + ct * 16 + l16;
            size_t base = ((size_t)(b * C + co)) * HW + n0w + nt * 16 + q * 4;
            float4 cv = *(const float4*)&xc[base];
            float bov = bo[co];
            float4 o;
            o.x = acc[nt][ct][0] + bov + cv.x;
            o.y = acc[nt][ct][1] + bov + cv.y;
            o.z = acc[nt][ct][2] + bov + cv.z;
            o.w = acc[nt][ct][3] + bov + cv.w;
            *(float4*)&out[base] = o;
        }
}

// ---------------------------------------------------------------------------
extern "C" void kernel_launch(void* const* d_in, const int* in_sizes, int n_in,
                              void* d_out, int out_size, void* d_ws, size_t ws_size,
                              hipStream_t stream)
{
    const float* content = (const float*)d_in[0];
    const float* style   = (const float*)d_in[1];
    const float* Wf = (const float*)d_in[2];
    const float* bf = (const float*)d_in[3];
    const float* Wg = (const float*)d_in[4];
    // d_in[5] = bg: provably unused (softmax row-constant)
    const float* Wh = (const float*)d_in[6];
    const float* bh = (const float*)d_in[7];
    const float* Wo = (const float*)d_in[8];
    const float* bo = (const float*)d_in[9];
    float* out = (float*)d_out;
    char* ws = (char*)d_ws;

    transpose_stats_kernel<<<4096, 256, 0, stream>>>(content, style, ws);
    finalize_stats_kernel<<<16, 256, 0, stream>>>(ws);
    precompute_kernel<<<522, 256, 0, stream>>>(Wf, Wg, Wo, Wh, bf, bh, ws);
    scaleA_kernel<<<512, 256, 0, stream>>>(ws);
    precompute_v_kernel<<<64, 256, 0, stream>>>(Wg, ws);
    prep_gemm_kernel<<<1024, 256, 0, stream>>>(ws);
    t_kernel<<<256, 256, 0, stream>>>(ws);
    qk_kernel<<<2048, 256, 0, stream>>>(ws);
    scale_kernel<<<256, 256, 0, stream>>>(ws);
    pv_kernel<<<1024, 256, 0, stream>>>(content, bo, out, ws);
}

// Round 9
// 463.161 us; speedup vs baseline: 1.0086x; 1.0086x over previous
//
#include <hip/hip_runtime.h>

#define C 512
#define HW 4096
#define EPSV 1e-5f

typedef _Float16 fp16x8 __attribute__((ext_vector_type(8)));
typedef _Float16 fp16x4 __attribute__((ext_vector_type(4)));
typedef float f32x4 __attribute__((ext_vector_type(4)));

// ---- workspace layout (bytes) ----
#define OFF_MC    (0)
#define OFF_RC    (8192)
#define OFF_MS    (16384)
#define OFF_RS    (24576)
#define OFF_BETAF (32768)
#define OFF_V     (40960)
#define OFF_BZ    (49152)
#define OFF_T     (65536)                      // t[b][m] f32, 64 KB
#define OFF_SP    (131072)                     // stats partials (2MB); reused as As f16 after finalize
#define OFF_A     (OFF_SP + 2097152)           // 1 MB (A f32)
#define OFF_WZ    (OFF_A + 1048576)            // 1 MB (Wz f16 FT, 512KB used)
#define OFF_XCT   (OFF_WZ + 1048576)           // 16 MB (fragment-tiled; reused as Scl after qk)
#define OFF_XST   (OFF_XCT + 16777216)         // 16 MB (fragment-tiled)
#define OFF_KT    (OFF_XST + 16777216)         // 16 MB (fragment-tiled)
#define OFF_HM    (OFF_KT + 16777216)          // 16 MB (fragment-tiled Hp layout)
#define OFF_ML    (OFF_HM + 16777216)          // float2[4][4096][64] = 8 MB
#define OFF_S     (OFF_ML + 8388608)           // f16 [4] fragment-tiled [4096][4096] = 128 MB
// total ~= 204 MB

// Fragment-tiled layout for transposed f16 tensors (xcT, xsT, Kt) and 512x512
// operands (As, Wz): elem (row n, col c) ->
//   ((n>>4)*16 + (c>>5))*512 + ((c>>3)&3)*128 + (n&15)*8 + (c&7)
#define FT_IDX(n, c) ((((size_t)((n) >> 4) * 16 + ((c) >> 5)) * 512) + \
                      ((((c) >> 3) & 3) * 128) + (((n) & 15) * 8) + ((c) & 7))

// S fragment-tiled (per batch, n,m in [0,4096)):
#define SFT_IDX(n, m) ((((size_t)((n) >> 4) * 128 + ((m) >> 5)) * 512) + \
                       ((((m) >> 3) & 3) * 128) + (((n) & 15) * 8) + ((m) & 7))

// Hp tiled layout (per batch b): (co, m) at ((co>>4)*512 + (m>>3))*128 + (co&15)*8 + (m&7)

// ---------------------------------------------------------------------------
// 1) fused transpose + f16 cast + partial stats. COALESCED fp32 reads
//    (4 x 256B segments per instr) + LDS partial-sum stats reduce
//    (2 ds_writes per float4 instead of 8 shuffles + 8 VALU).
// ---------------------------------------------------------------------------
__global__ void transpose_stats_kernel(const float* __restrict__ xc, const float* __restrict__ xs,
                                       char* __restrict__ ws)
{
    int bx = blockIdx.x;                  // 4096 = 2 * 4 * 8 * 64
    int tensor = bx >> 11, b = (bx >> 9) & 3, c0 = ((bx >> 6) & 7) * 64, n0 = (bx & 63) * 64;
    const float* src = tensor ? xs : xc;
    _Float16* dst = (_Float16*)(ws + (tensor ? OFF_XST : OFF_XCT));
    float2* part = (float2*)(ws + OFF_SP);

    __shared__ _Float16 tile[64][72];
    __shared__ float pS[64][16], pSS[64][16];

    int tid = threadIdx.x, w = tid >> 6, lane = tid & 63, cq = lane >> 4, l16 = lane & 15;
    #pragma unroll
    for (int k = 0; k < 4; k++) {
        int cr = w * 16 + k * 4 + cq;                 // c offset within tile (bijective over k,w,cq)
        int nf = l16 * 4;                             // n offset within tile
        float4 v = *(const float4*)(src + ((size_t)(b * C + c0 + cr)) * HW + n0 + nf);
        pS[cr][l16] = v.x + v.y + v.z + v.w;
        pSS[cr][l16] = v.x * v.x + v.y * v.y + v.z * v.z + v.w * v.w;
        tile[nf][cr] = (_Float16)v.x; tile[nf + 1][cr] = (_Float16)v.y;
        tile[nf + 2][cr] = (_Float16)v.z; tile[nf + 3][cr] = (_Float16)v.w;
    }
    __syncthreads();
    if (tid < 64) {
        float S = 0.f, SS = 0.f;
        #pragma unroll
        for (int j = 0; j < 16; j++) { S += pS[tid][j]; SS += pSS[tid][j]; }
        part[((size_t)((tensor * 4 + b) * 512 + c0 + tid)) * 64 + (n0 >> 6)] =
            make_float2(S, SS);
    }
    _Float16* dstB = dst + (size_t)b * HW * C;
    #pragma unroll
    for (int i = 0; i < 2; i++) {
        int g = tid + i * 256, row = g >> 3, c8 = (g & 7) * 8;
        int n = n0 + row, c = c0 + c8;
        *(fp16x8*)&dstB[FT_IDX(n, c)] = *(const fp16x8*)&tile[row][c8];
    }
}

// ---------------------------------------------------------------------------
// 1b) finalize stats
// ---------------------------------------------------------------------------
__global__ void finalize_stats_kernel(char* __restrict__ ws)
{
    int ch = blockIdx.x * 256 + threadIdx.x;       // 16 blocks -> 4096 channels
    const float2* part = (const float2*)(ws + OFF_SP) + (size_t)ch * 64;
    float S = 0.f, SS = 0.f;
    for (int k = 0; k < 64; k++) { float2 v = part[k]; S += v.x; SS += v.y; }
    int tensor = ch >> 11, rem = ch & 2047;
    float m = S / (float)HW;
    float var = (SS - S * m) / (float)(HW - 1) + EPSV;   // unbiased (n-1) + EPS
    ((float*)(ws + (tensor ? OFF_MS : OFF_MC)))[rem] = m;
    ((float*)(ws + (tensor ? OFF_RS : OFF_RC)))[rem] = rsqrtf(var);
}

// ---------------------------------------------------------------------------
// 2) small precomputes: A = Wf^T Wg (f32), Wz = Wo Wh (f16 FT!), betaf, bz
// ---------------------------------------------------------------------------
__global__ void precompute_kernel(const float* __restrict__ Wf, const float* __restrict__ Wg,
                                  const float* __restrict__ Wo, const float* __restrict__ Wh,
                                  const float* __restrict__ bf, const float* __restrict__ bh,
                                  char* __restrict__ ws)
{
    float* A = (float*)(ws + OFF_A);
    _Float16* Wz16 = (_Float16*)(ws + OFF_WZ);
    float* betaf = (float*)(ws + OFF_BETAF);
    float* bz = (float*)(ws + OFF_BZ);
    const float* mc = (const float*)(ws + OFF_MC);
    const float* rc = (const float*)(ws + OFF_RC);
    int bx = blockIdx.x, t = threadIdx.x;
    if (bx < 512) {                              // A or Wz, 2 output rows per block
        bool isA = bx < 256;
        int r0 = (isA ? bx : bx - 256) * 2;
        float a00 = 0.f, a01 = 0.f, a10 = 0.f, a11 = 0.f;
        for (int k = 0; k < C; k++) {
            float r0v, r1v, c0v, c1v;
            if (isA) {                           // A[i][j] = sum_co Wf[co][i]*Wg[co][j]
                r0v = Wf[k * C + r0]; r1v = Wf[k * C + r0 + 1];
                c0v = Wg[k * C + t];  c1v = Wg[k * C + t + 256];
            } else {                             // Wz[o][j] = sum_i Wo[o][i]*Wh[i][j]
                r0v = Wo[r0 * C + k]; r1v = Wo[(r0 + 1) * C + k];
                c0v = Wh[k * C + t];  c1v = Wh[k * C + t + 256];
            }
            a00 += r0v * c0v; a01 += r0v * c1v;
            a10 += r1v * c0v; a11 += r1v * c1v;
        }
        if (isA) {
            A[r0 * C + t] = a00;       A[r0 * C + t + 256] = a01;
            A[(r0 + 1) * C + t] = a10; A[(r0 + 1) * C + t + 256] = a11;
        } else {
            Wz16[FT_IDX(r0, t)] = (_Float16)a00;
            Wz16[FT_IDX(r0, t + 256)] = (_Float16)a01;
            Wz16[FT_IDX(r0 + 1, t)] = (_Float16)a10;
            Wz16[FT_IDX(r0 + 1, t + 256)] = (_Float16)a11;
        }
    } else if (bx < 520) {                       // betaf[b][co] = bf[co] - sum_i Wf[co][i]*mc*rc
        int g = (bx - 512) * 256 + t, b = g >> 9, co = g & 511;
        float acc = 0.f;
        for (int i = 0; i < C; i++) acc += Wf[co * C + i] * mc[b * C + i] * rc[b * C + i];
        betaf[g] = bf[co] - acc;
    } else {                                     // bz[co] = sum_i Wo[co][i]*bh[i]
        int co = (bx - 520) * 256 + t;
        float acc = 0.f;
        for (int i = 0; i < C; i++) acc += Wo[co * C + i] * bh[i];
        bz[co] = acc;
    }
}

// ---------------------------------------------------------------------------
// 2b) As[b] = diag(rc_b) * A * diag(rs_b), f16 FT layout (into dead SP buf).
// ---------------------------------------------------------------------------
__global__ void scaleA_kernel(char* __restrict__ ws)
{
    const float* __restrict__ A = (const float*)(ws + OFF_A);
    const float* __restrict__ rc = (const float*)(ws + OFF_RC);
    const float* __restrict__ rs = (const float*)(ws + OFF_RS);
    _Float16* __restrict__ As = (_Float16*)(ws + OFF_SP);

    int gid = blockIdx.x * 256 + threadIdx.x;   // 131072 = 4b * 512 sub * 64
    int b = gid >> 15, rem = gid & 32767;
    int sub = rem >> 6, low6 = rem & 63;
    int r16 = sub >> 4, cb4 = sub & 15;
    int q = low6 >> 4, l16 = low6 & 15;
    int r = r16 * 16 + l16, j0 = (cb4 * 4 + q) * 8;

    float4 a0 = *(const float4*)&A[r * C + j0];
    float4 a1 = *(const float4*)&A[r * C + j0 + 4];
    float4 s0 = *(const float4*)&rs[b * C + j0];
    float4 s1 = *(const float4*)&rs[b * C + j0 + 4];
    float rcv = rc[b * C + r];
    fp16x8 o;
    o[0] = (_Float16)(a0.x * rcv * s0.x); o[1] = (_Float16)(a0.y * rcv * s0.y);
    o[2] = (_Float16)(a0.z * rcv * s0.z); o[3] = (_Float16)(a0.w * rcv * s0.w);
    o[4] = (_Float16)(a1.x * rcv * s1.x); o[5] = (_Float16)(a1.y * rcv * s1.y);
    o[6] = (_Float16)(a1.z * rcv * s1.z); o[7] = (_Float16)(a1.w * rcv * s1.w);
    *(fp16x8*)&As[(size_t)b * 262144 + (size_t)sub * 512 + low6 * 8] = o;
}

// v[b][j] = rs[b][j] * sum_co betaf[b][co]*Wg[co][j]
__global__ void precompute_v_kernel(const float* __restrict__ Wg, char* __restrict__ ws)
{
    const float* betaf = (const float*)(ws + OFF_BETAF);
    const float* rs = (const float*)(ws + OFF_RS);
    float* v = (float*)(ws + OFF_V);
    int g = blockIdx.x * 32 + (threadIdx.x >> 3);   // 0..2047 output index
    int b = g >> 9, j = g & 511, cq = threadIdx.x & 7;
    float acc = 0.f;
    for (int co = cq * 64; co < cq * 64 + 64; co++) acc += betaf[b * C + co] * Wg[co * C + j];
    acc += __shfl_xor(acc, 1);
    acc += __shfl_xor(acc, 2);
    acc += __shfl_xor(acc, 4);
    if (cq == 0) v[g] = rs[b * C + j] * acc;
}

// ---------------------------------------------------------------------------
// 3) fused prep GEMM -> Kt (f16 FT) and Hp (f16 tiled). All loads wave-linear.
// ---------------------------------------------------------------------------
__global__ void __launch_bounds__(256) prep_gemm_kernel(char* __restrict__ ws)
{
    const _Float16* __restrict__ As = (const _Float16*)(ws + OFF_SP);
    const _Float16* __restrict__ Wz16 = (const _Float16*)(ws + OFF_WZ);
    const float* __restrict__ bz = (const float*)(ws + OFF_BZ);
    const _Float16* __restrict__ xsT = (const _Float16*)(ws + OFF_XST);
    _Float16* __restrict__ Kt = (_Float16*)(ws + OFF_KT);
    _Float16* __restrict__ Hp = (_Float16*)(ws + OFF_HM);

    int bx = blockIdx.x;                 // 1024 = 4b * 8 rowblk * 32 mblk
    int b = bx & 3, rest = bx >> 2;
    int r128 = rest >> 5, mb = rest & 31;
    int r0 = r128 * 128, m0 = mb * 128;
    int w = threadIdx.x >> 6, lane = threadIdx.x & 63, q = lane >> 4, l16 = lane & 15;
    int wr = (w & 1) * 64, wm = (w >> 1) * 64;
    bool isK = (r0 < 512);
    int rbase = (isK ? r0 : r0 - 512) + wr;

    f32x4 zz = {0.f, 0.f, 0.f, 0.f};
    f32x4 acc[4][4];
    #pragma unroll
    for (int rt = 0; rt < 4; rt++)
        #pragma unroll
        for (int mt = 0; mt < 4; mt++) acc[rt][mt] = zz;

    const _Float16* ap = (isK ? As + (size_t)b * 262144 : Wz16)
                         + (size_t)(rbase >> 4) * 8192 + q * 128 + l16 * 8;
    const _Float16* xb = xsT + (size_t)b * HW * C
                             + (size_t)((m0 + wm) >> 4) * 8192 + q * 128 + l16 * 8;

    for (int ks = 0; ks < 16; ks++) {
        fp16x8 afr[4], bfr[4];
        #pragma unroll
        for (int rt = 0; rt < 4; rt++)
            afr[rt] = *(const fp16x8*)(ap + (size_t)rt * 8192 + ks * 512);
        #pragma unroll
        for (int mt = 0; mt < 4; mt++)
            bfr[mt] = *(const fp16x8*)(xb + (size_t)(mt * 16 + ks) * 512);
        #pragma unroll
        for (int rt = 0; rt < 4; rt++)
            #pragma unroll
            for (int mt = 0; mt < 4; mt++)
                acc[rt][mt] = __builtin_amdgcn_mfma_f32_16x16x32_f16(afr[rt], bfr[mt], acc[rt][mt], 0, 0, 0);
    }

    if (isK) {
        _Float16* KtB = Kt + (size_t)b * HW * C;
        #pragma unroll
        for (int rt = 0; rt < 4; rt++)
            #pragma unroll
            for (int mt = 0; mt < 4; mt++) {
                int m = m0 + wm + mt * 16 + l16;
                int cb = r0 + wr + rt * 16 + q * 4;
                fp16x4 h;
                h[0] = (_Float16)acc[rt][mt][0]; h[1] = (_Float16)acc[rt][mt][1];
                h[2] = (_Float16)acc[rt][mt][2]; h[3] = (_Float16)acc[rt][mt][3];
                *(fp16x4*)&KtB[FT_IDX(m, cb)] = h;
            }
    } else {
        _Float16* HpB = Hp + (size_t)b * 2097152;
        #pragma unroll
        for (int rt = 0; rt < 4; rt++) {
            float bzv[4];
            #pragma unroll
            for (int reg = 0; reg < 4; reg++) bzv[reg] = bz[rbase + rt * 16 + q * 4 + reg];
            #pragma unroll
            for (int mt = 0; mt < 4; mt++) {
                int m = m0 + wm + mt * 16 + l16;
                int mbase = (m >> 3) * 128 + (m & 7);
                #pragma unroll
                for (int reg = 0; reg < 4; reg++) {
                    int co = rbase + rt * 16 + q * 4 + reg;
                    HpB[(size_t)(co >> 4) * 65536 + mbase + (co & 15) * 8] =
                        (_Float16)(acc[rt][mt][reg] + bzv[reg]);
                }
            }
        }
    }
}

// ---------------------------------------------------------------------------
// 4) t[b][m] = sum_j v[b][j] * xsT[b][m][j] — wave-linear FT loads.
// ---------------------------------------------------------------------------
__global__ void t_kernel(char* __restrict__ ws)
{
    const float* v = (const float*)(ws + OFF_V);
    const _Float16* __restrict__ xsT = (const _Float16*)(ws + OFF_XST);
    float* tG = (float*)(ws + OFF_T);
    int bx = blockIdx.x;                      // 256 = 4 b * 64 mblk(64m)
    int b = bx >> 6, mb = bx & 63;
    int tid = threadIdx.x, w = tid >> 6, lane = tid & 63, q = lane >> 4, l16 = lane & 15;
    int M16 = mb * 4 + w;                     // m-subtile; m = M16*16 + l16
    const _Float16* p = xsT + (size_t)b * HW * C + (size_t)M16 * 8192 + q * 128 + l16 * 8;
    const float* vp = v + b * C + q * 8;
    float acc = 0.f;
    #pragma unroll
    for (int st = 0; st < 16; st++) {
        fp16x8 xv = *(const fp16x8*)(p + st * 512);
        float4 v0 = *(const float4*)(vp + st * 32);
        float4 v1 = *(const float4*)(vp + st * 32 + 4);
        acc += (float)xv[0] * v0.x + (float)xv[1] * v0.y + (float)xv[2] * v0.z + (float)xv[3] * v0.w
             + (float)xv[4] * v1.x + (float)xv[5] * v1.y + (float)xv[6] * v1.z + (float)xv[7] * v1.w;
    }
    acc += __shfl_xor(acc, 16);
    acc += __shfl_xor(acc, 32);
    if (q == 0) tG[b * HW + M16 * 16 + l16] = acc;
}

// ---------------------------------------------------------------------------
// 5) pass A: S-tile = Q @ Kt^T (128x128, K=512) + t[m]; per-(row, 64-m-tile)
//    max & sumexp; stores p = exp(s - tilemax) f16 to S (FRAGMENT-TILED),
//    (max,sum) to ML. xcT/Kt fragment-tiled: A/B loads 1KB wave-linear.
//    (reverted to the r7 128x128 version — big-tile was neutral-negative)
// ---------------------------------------------------------------------------
__global__ void __launch_bounds__(256, 4) qk_kernel(char* __restrict__ ws)
{
    const _Float16* __restrict__ xcT = (const _Float16*)(ws + OFF_XCT);
    const _Float16* __restrict__ Kt = (const _Float16*)(ws + OFF_KT);
    const float* __restrict__ tG = (const float*)(ws + OFF_T);
    float2* __restrict__ ML = (float2*)(ws + OFF_ML);
    _Float16* __restrict__ Sg = (_Float16*)(ws + OFF_S);

    int bx = blockIdx.x;                  // 4096: low3 = b*2+mhi (XCD-pinned)
    int b = (bx >> 1) & 3, mhi = bx & 1;
    int rest = bx >> 3, mlo = rest & 15, ntile = rest >> 4;
    int m0 = (mhi * 16 + mlo) * 128, n0 = ntile * 128;
    int tid = threadIdx.x, w = tid >> 6, lane = tid & 63, q = lane >> 4, l16 = lane & 15;
    int wn = (w & 1) * 64, wm = (w >> 1) * 64;

    const _Float16* ab = xcT + (size_t)b * HW * C
                             + (size_t)((n0 + wn) >> 4) * 8192 + q * 128 + l16 * 8;
    const _Float16* bb = Kt + (size_t)b * HW * C
                            + (size_t)((m0 + wm) >> 4) * 8192 + q * 128 + l16 * 8;

    f32x4 zz = {0.f, 0.f, 0.f, 0.f};
    f32x4 acc[4][4];
    #pragma unroll
    for (int nt = 0; nt < 4; nt++)
        #pragma unroll
        for (int mt = 0; mt < 4; mt++) acc[nt][mt] = zz;

    #pragma unroll 4
    for (int ks = 0; ks < 16; ks++) {
        fp16x8 afr[4], bfr[4];
        #pragma unroll
        for (int nt = 0; nt < 4; nt++)
            afr[nt] = *(const fp16x8*)(ab + (size_t)(nt * 16 + ks) * 512);
        #pragma unroll
        for (int mt = 0; mt < 4; mt++)
            bfr[mt] = *(const fp16x8*)(bb + (size_t)(mt * 16 + ks) * 512);
        #pragma unroll
        for (int nt = 0; nt < 4; nt++)
            #pragma unroll
            for (int mt = 0; mt < 4; mt++)
                acc[nt][mt] = __builtin_amdgcn_mfma_f32_16x16x32_f16(afr[nt], bfr[mt], acc[nt][mt], 0, 0, 0);
    }

    // ---- epilogue: + t[m], per-row tile max / exp / sum ----
    float tv[4];
    #pragma unroll
    for (int mt = 0; mt < 4; mt++) tv[mt] = tG[b * HW + m0 + wm + mt * 16 + l16];
    #pragma unroll
    for (int nt = 0; nt < 4; nt++)
        #pragma unroll
        for (int mt = 0; mt < 4; mt++)
            #pragma unroll
            for (int reg = 0; reg < 4; reg++) acc[nt][mt][reg] += tv[mt];

    float rm[4][4], sum[4][4];
    #pragma unroll
    for (int nt = 0; nt < 4; nt++)
        #pragma unroll
        for (int reg = 0; reg < 4; reg++)
            rm[nt][reg] = fmaxf(fmaxf(acc[nt][0][reg], acc[nt][1][reg]),
                                fmaxf(acc[nt][2][reg], acc[nt][3][reg]));
    #pragma unroll
    for (int s = 1; s < 16; s <<= 1)
        #pragma unroll
        for (int nt = 0; nt < 4; nt++)
            #pragma unroll
            for (int reg = 0; reg < 4; reg++)
                rm[nt][reg] = fmaxf(rm[nt][reg], __shfl_xor(rm[nt][reg], s));
    #pragma unroll
    for (int nt = 0; nt < 4; nt++)
        #pragma unroll
        for (int reg = 0; reg < 4; reg++) sum[nt][reg] = 0.f;
    #pragma unroll
    for (int nt = 0; nt < 4; nt++)
        #pragma unroll
        for (int mt = 0; mt < 4; mt++)
            #pragma unroll
            for (int reg = 0; reg < 4; reg++) {
                float pv = __expf(acc[nt][mt][reg] - rm[nt][reg]);
                acc[nt][mt][reg] = pv;
                sum[nt][reg] += pv;
            }
    #pragma unroll
    for (int s = 1; s < 16; s <<= 1)
        #pragma unroll
        for (int nt = 0; nt < 4; nt++)
            #pragma unroll
            for (int reg = 0; reg < 4; reg++)
                sum[nt][reg] += __shfl_xor(sum[nt][reg], s);

    int tl = (m0 + wm) >> 6;
    if (l16 == 0) {
        #pragma unroll
        for (int nt = 0; nt < 4; nt++)
            #pragma unroll
            for (int reg = 0; reg < 4; reg++)
                ML[((size_t)(b * HW + n0 + wn + nt * 16 + q * 4 + reg)) * 64 + tl] =
                    make_float2(rm[nt][reg], sum[nt][reg]);
    }

    // ---- f16 + LDS transpose-spill, then 16B stores to fragment-tiled S ----
    __shared__ _Float16 Pl[4][64][72];
    #pragma unroll
    for (int nt = 0; nt < 4; nt++)
        #pragma unroll
        for (int mt = 0; mt < 4; mt++)
            #pragma unroll
            for (int reg = 0; reg < 4; reg++)
                Pl[w][nt * 16 + q * 4 + reg][mt * 16 + l16] = (_Float16)acc[nt][mt][reg];
    __syncthreads();
    _Float16* SgB = Sg + (size_t)b * 16777216;
    #pragma unroll
    for (int i = 0; i < 8; i++) {
        int row = i * 8 + (lane >> 3), c8 = (lane & 7) * 8;
        int n = n0 + wn + row, m = m0 + wm + c8;
        *(fp16x8*)&SgB[SFT_IDX(n, m)] = *(const fp16x8*)&Pl[w][row][c8];
    }
}

// ---------------------------------------------------------------------------
// 5b) per-row global softmax scales: Scl[b][tile][n] = e^(m_tile - M)/L (f32)
// ---------------------------------------------------------------------------
__global__ void __launch_bounds__(256) scale_kernel(char* __restrict__ ws)
{
    const float* __restrict__ mlf0 = (const float*)(ws + OFF_ML);
    float* __restrict__ Scl = (float*)(ws + OFF_XCT);
    __shared__ float mlv[64][129];       // [row][2*tile + {0:max,1:sum}]
    __shared__ float Ms[64], Li[64];

    int g0 = blockIdx.x * 64;            // global row base (b*4096 + n), 16384 total
    int tid = threadIdx.x;
    const float* mlf = mlf0 + (size_t)g0 * 128;   // 64 rows x 128 f32 (float2[64])

    #pragma unroll
    for (int i = 0; i < 8; i++) {
        int f4 = i * 256 + tid;          // 2048 float4 = 64 rows x 32
        int row = f4 >> 5, c4 = (f4 & 31) * 4;
        float4 v = *(const float4*)(mlf + row * 128 + c4);
        mlv[row][c4] = v.x; mlv[row][c4 + 1] = v.y;
        mlv[row][c4 + 2] = v.z; mlv[row][c4 + 3] = v.w;
    }
    __syncthreads();
    if (tid < 64) {
        float M = -1e30f;
        #pragma unroll
        for (int k = 0; k < 64; k++) M = fmaxf(M, mlv[tid][k * 2]);
        float L = 0.f;
        #pragma unroll
        for (int k = 0; k < 64; k++) L += mlv[tid][k * 2 + 1] * __expf(mlv[tid][k * 2] - M);
        Ms[tid] = M; Li[tid] = 1.f / L;
    }
    __syncthreads();
    int b = g0 >> 12, nbase = g0 & 4095;
    float* sp = Scl + (size_t)b * 262144 + nbase;
    int row = tid & 63, tsub = tid >> 6;
    #pragma unroll
    for (int pass = 0; pass < 16; pass++) {
        int tile = pass * 4 + tsub;
        sp[(size_t)tile * 4096 + row] = __expf(mlv[row][tile * 2] - Ms[row]) * Li[row];
    }
}

// ---------------------------------------------------------------------------
// 6) pass C: O = (p * scale) @ Hp^T — LDS-Hp pipeline (unchanged from r6).
// ---------------------------------------------------------------------------
__global__ void __launch_bounds__(256, 4) pv_kernel(const float* __restrict__ xc,
                                                    const float* __restrict__ bo,
                                                    float* __restrict__ out,
                                                    char* __restrict__ ws)
{
    const _Float16* __restrict__ Sft = (const _Float16*)(ws + OFF_S);
    const _Float16* __restrict__ Hp = (const _Float16*)(ws + OFF_HM);
    const float* __restrict__ Scl = (const float*)(ws + OFF_XCT);

    int bx = blockIdx.x;                 // 1024 = 32 ntb * 8 cog * 4 b
    int b = bx & 3, cog = (bx >> 2) & 7, ntb = bx >> 5;
    int co0 = cog * 64;
    int tid = threadIdx.x, w = tid >> 6, lane = tid & 63, q = lane >> 4, l16 = lane & 15;
    int n0w = ntb * 128 + w * 32;

    __shared__ _Float16 Hl[2][4096];     // 8KB chunk slice (64co x 64keys), dbuf

    int ln64 = lane;
    const _Float16* hsrc = Hp + (size_t)b * 2097152
                              + (size_t)((co0 >> 4) + w) * 65536 + ln64 * 8;
    const _Float16* sb = Sft + (size_t)b * 16777216
                             + (size_t)(ntb * 8 + w * 2) * 65536 + q * 128 + l16 * 8;
    const float* sc = Scl + (size_t)b * 262144 + n0w + q * 4;

    // prologue: stage chunk 0
    {
        fp16x8 s0 = *(const fp16x8*)(hsrc);
        fp16x8 s1 = *(const fp16x8*)(hsrc + 512);
        *(fp16x8*)&Hl[0][w * 1024 + ln64 * 8] = s0;
        *(fp16x8*)&Hl[0][w * 1024 + 512 + ln64 * 8] = s1;
    }
    __syncthreads();

    f32x4 zz = {0.f, 0.f, 0.f, 0.f};
    f32x4 acc[2][4];
    #pragma unroll
    for (int nt = 0; nt < 2; nt++)
        #pragma unroll
        for (int ct = 0; ct < 4; ct++) acc[nt][ct] = zz;

    for (int chunk = 0; chunk < 64; chunk++) {
        int buf = chunk & 1;
        fp16x8 s0n, s1n;
        if (chunk < 63) {
            s0n = *(const fp16x8*)(hsrc + (chunk + 1) * 1024);
            s1n = *(const fp16x8*)(hsrc + (chunk + 1) * 1024 + 512);
        }

        f32x4 tmp[2][4];
        #pragma unroll
        for (int km = 0; km < 2; km++) {
            fp16x8 afr[2], bfr[4];
            #pragma unroll
            for (int nt = 0; nt < 2; nt++)
                afr[nt] = *(const fp16x8*)(sb + (size_t)nt * 65536 + (chunk * 2 + km) * 512);
            #pragma unroll
            for (int ct = 0; ct < 4; ct++)
                bfr[ct] = *(const fp16x8*)&Hl[buf][ct * 1024 + (km * 4 + q) * 128 + l16 * 8];
            #pragma unroll
            for (int nt = 0; nt < 2; nt++)
                #pragma unroll
                for (int ct = 0; ct < 4; ct++)
                    tmp[nt][ct] = __builtin_amdgcn_mfma_f32_16x16x32_f16(
                        afr[nt], bfr[ct], km == 0 ? zz : tmp[nt][ct], 0, 0, 0);
        }
        float4 sv0 = *(const float4*)(sc + chunk * 4096);
        float4 sv1 = *(const float4*)(sc + chunk * 4096 + 16);
        float sva[2][4] = {{sv0.x, sv0.y, sv0.z, sv0.w}, {sv1.x, sv1.y, sv1.z, sv1.w}};
        #pragma unroll
        for (int nt = 0; nt < 2; nt++)
            #pragma unroll
            for (int ct = 0; ct < 4; ct++)
                #pragma unroll
                for (int reg = 0; reg < 4; reg++)
                    acc[nt][ct][reg] += tmp[nt][ct][reg] * sva[nt][reg];

        if (chunk < 63) {
            *(fp16x8*)&Hl[buf ^ 1][w * 1024 + ln64 * 8] = s0n;
            *(fp16x8*)&Hl[buf ^ 1][w * 1024 + 512 + ln64 * 8] = s1n;
        }
        __syncthreads();
    }

    // ---- epilogue: + bo + content ----
    #pragma unroll
    for (int nt = 0; nt < 2; nt++)
        #pragma unroll
        for (int ct = 0; ct < 4; ct++) {
            int co = co0 + ct * 16 + l16;
            size_t base = ((size_t)(b * C + co)) * HW + n0w + nt * 16 + q * 4;
            float4 cv = *(const float4*)&xc[base];
            float bov = bo[co];
            float4 o;
            o.x = acc[nt][ct][0] + bov + cv.x;
            o.y = acc[nt][ct][1] + bov + cv.y;
            o.z = acc[nt][ct][2] + bov + cv.z;
            o.w = acc[nt][ct][3] + bov + cv.w;
            *(float4*)&out[base] = o;
        }
}

// ---------------------------------------------------------------------------
extern "C" void kernel_launch(void* const* d_in, const int* in_sizes, int n_in,
                              void* d_out, int out_size, void* d_ws, size_t ws_size,
                              hipStream_t stream)
{
    const float* content = (const float*)d_in[0];
    const float* style   = (const float*)d_in[1];
    const float* Wf = (const float*)d_in[2];
    const float* bf = (const float*)d_in[3];
    const float* Wg = (const float*)d_in[4];
    // d_in[5] = bg: provably unused (softmax row-constant)
    const float* Wh = (const float*)d_in[6];
    const float* bh = (const float*)d_in[7];
    const float* Wo = (const float*)d_in[8];
    const float* bo = (const float*)d_in[9];
    float* out = (float*)d_out;
    char* ws = (char*)d_ws;

    transpose_stats_kernel<<<4096, 256, 0, stream>>>(content, style, ws);
    finalize_stats_kernel<<<16, 256, 0, stream>>>(ws);
    precompute_kernel<<<522, 256, 0, stream>>>(Wf, Wg, Wo, Wh, bf, bh, ws);
    scaleA_kernel<<<512, 256, 0, stream>>>(ws);
    precompute_v_kernel<<<64, 256, 0, stream>>>(Wg, ws);
    prep_gemm_kernel<<<1024, 256, 0, stream>>>(ws);
    t_kernel<<<256, 256, 0, stream>>>(ws);
    qk_kernel<<<4096, 256, 0, stream>>>(ws);
    scale_kernel<<<256, 256, 0, stream>>>(ws);
    pv_kernel<<<1024, 256, 0, stream>>>(content, bo, out, ws);
}

// Round 10
// 459.487 us; speedup vs baseline: 1.0167x; 1.0080x over previous
//
#include <hip/hip_runtime.h>

#define C 512
#define HW 4096
#define EPSV 1e-5f

typedef _Float16 fp16x8 __attribute__((ext_vector_type(8)));
typedef _Float16 fp16x4 __attribute__((ext_vector_type(4)));
typedef float f32x4 __attribute__((ext_vector_type(4)));

// ---- workspace layout (bytes) ----
#define OFF_MC    (0)
#define OFF_RC    (8192)
#define OFF_MS    (16384)
#define OFF_RS    (24576)
#define OFF_BETAF (32768)
#define OFF_V     (40960)
#define OFF_BZ    (49152)
#define OFF_T     (65536)                      // t[b][m] f32, 64 KB
#define OFF_SP    (131072)                     // stats partials (2MB); reused as As f16 after finalize
#define OFF_A     (OFF_SP + 2097152)           // 1 MB (A f32)
#define OFF_WZ    (OFF_A + 1048576)            // 1 MB (Wz f16 FT, 512KB used)
#define OFF_XCT   (OFF_WZ + 1048576)           // 16 MB (fragment-tiled; reused as Scl after qk)
#define OFF_XST   (OFF_XCT + 16777216)         // 16 MB (fragment-tiled)
#define OFF_KT    (OFF_XST + 16777216)         // 16 MB (fragment-tiled)
#define OFF_HM    (OFF_KT + 16777216)          // 16 MB (fragment-tiled Hp layout)
#define OFF_ML    (OFF_HM + 16777216)          // float2[4][4096][64] = 8 MB
#define OFF_S     (OFF_ML + 8388608)           // f16 [4] fragment-tiled [4096][4096] = 128 MB
// total ~= 204 MB

// Fragment-tiled layout for transposed f16 tensors (xcT, xsT, Kt) and 512x512
// operands (As, Wz): elem (row n, col c) ->
//   ((n>>4)*16 + (c>>5))*512 + ((c>>3)&3)*128 + (n&15)*8 + (c&7)
#define FT_IDX(n, c) ((((size_t)((n) >> 4) * 16 + ((c) >> 5)) * 512) + \
                      ((((c) >> 3) & 3) * 128) + (((n) & 15) * 8) + ((c) & 7))

// S fragment-tiled (per batch, n,m in [0,4096)):
#define SFT_IDX(n, m) ((((size_t)((n) >> 4) * 128 + ((m) >> 5)) * 512) + \
                       ((((m) >> 3) & 3) * 128) + (((n) & 15) * 8) + ((m) & 7))

// Hp tiled layout (per batch b): (co, m) at ((co>>4)*512 + (m>>3))*128 + (co&15)*8 + (m&7)

// ---------------------------------------------------------------------------
// 1) fused transpose + f16 cast + partial stats. COALESCED fp32 reads
//    (4 x 256B segments per instr) + LDS partial-sum stats reduce.
// ---------------------------------------------------------------------------
__global__ void transpose_stats_kernel(const float* __restrict__ xc, const float* __restrict__ xs,
                                       char* __restrict__ ws)
{
    int bx = blockIdx.x;                  // 4096 = 2 * 4 * 8 * 64
    int tensor = bx >> 11, b = (bx >> 9) & 3, c0 = ((bx >> 6) & 7) * 64, n0 = (bx & 63) * 64;
    const float* src = tensor ? xs : xc;
    _Float16* dst = (_Float16*)(ws + (tensor ? OFF_XST : OFF_XCT));
    float2* part = (float2*)(ws + OFF_SP);

    __shared__ _Float16 tile[64][72];
    __shared__ float pS[64][16], pSS[64][16];

    int tid = threadIdx.x, w = tid >> 6, lane = tid & 63, cq = lane >> 4, l16 = lane & 15;
    #pragma unroll
    for (int k = 0; k < 4; k++) {
        int cr = w * 16 + k * 4 + cq;                 // c offset within tile (bijective over k,w,cq)
        int nf = l16 * 4;                             // n offset within tile
        float4 v = *(const float4*)(src + ((size_t)(b * C + c0 + cr)) * HW + n0 + nf);
        pS[cr][l16] = v.x + v.y + v.z + v.w;
        pSS[cr][l16] = v.x * v.x + v.y * v.y + v.z * v.z + v.w * v.w;
        tile[nf][cr] = (_Float16)v.x; tile[nf + 1][cr] = (_Float16)v.y;
        tile[nf + 2][cr] = (_Float16)v.z; tile[nf + 3][cr] = (_Float16)v.w;
    }
    __syncthreads();
    if (tid < 64) {
        float S = 0.f, SS = 0.f;
        #pragma unroll
        for (int j = 0; j < 16; j++) { S += pS[tid][j]; SS += pSS[tid][j]; }
        part[((size_t)((tensor * 4 + b) * 512 + c0 + tid)) * 64 + (n0 >> 6)] =
            make_float2(S, SS);
    }
    _Float16* dstB = dst + (size_t)b * HW * C;
    #pragma unroll
    for (int i = 0; i < 2; i++) {
        int g = tid + i * 256, row = g >> 3, c8 = (g & 7) * 8;
        int n = n0 + row, c = c0 + c8;
        *(fp16x8*)&dstB[FT_IDX(n, c)] = *(const fp16x8*)&tile[row][c8];
    }
}

// ---------------------------------------------------------------------------
// 1b) finalize stats
// ---------------------------------------------------------------------------
__global__ void finalize_stats_kernel(char* __restrict__ ws)
{
    int ch = blockIdx.x * 256 + threadIdx.x;       // 16 blocks -> 4096 channels
    const float2* part = (const float2*)(ws + OFF_SP) + (size_t)ch * 64;
    float S = 0.f, SS = 0.f;
    for (int k = 0; k < 64; k++) { float2 v = part[k]; S += v.x; SS += v.y; }
    int tensor = ch >> 11, rem = ch & 2047;
    float m = S / (float)HW;
    float var = (SS - S * m) / (float)(HW - 1) + EPSV;   // unbiased (n-1) + EPS
    ((float*)(ws + (tensor ? OFF_MS : OFF_MC)))[rem] = m;
    ((float*)(ws + (tensor ? OFF_RS : OFF_RC)))[rem] = rsqrtf(var);
}

// ---------------------------------------------------------------------------
// 2) small precomputes: A = Wf^T Wg (f32), Wz = Wo Wh (f16 FT!), betaf, bz
// ---------------------------------------------------------------------------
__global__ void precompute_kernel(const float* __restrict__ Wf, const float* __restrict__ Wg,
                                  const float* __restrict__ Wo, const float* __restrict__ Wh,
                                  const float* __restrict__ bf, const float* __restrict__ bh,
                                  char* __restrict__ ws)
{
    float* A = (float*)(ws + OFF_A);
    _Float16* Wz16 = (_Float16*)(ws + OFF_WZ);
    float* betaf = (float*)(ws + OFF_BETAF);
    float* bz = (float*)(ws + OFF_BZ);
    const float* mc = (const float*)(ws + OFF_MC);
    const float* rc = (const float*)(ws + OFF_RC);
    int bx = blockIdx.x, t = threadIdx.x;
    if (bx < 512) {                              // A or Wz, 2 output rows per block
        bool isA = bx < 256;
        int r0 = (isA ? bx : bx - 256) * 2;
        float a00 = 0.f, a01 = 0.f, a10 = 0.f, a11 = 0.f;
        for (int k = 0; k < C; k++) {
            float r0v, r1v, c0v, c1v;
            if (isA) {                           // A[i][j] = sum_co Wf[co][i]*Wg[co][j]
                r0v = Wf[k * C + r0]; r1v = Wf[k * C + r0 + 1];
                c0v = Wg[k * C + t];  c1v = Wg[k * C + t + 256];
            } else {                             // Wz[o][j] = sum_i Wo[o][i]*Wh[i][j]
                r0v = Wo[r0 * C + k]; r1v = Wo[(r0 + 1) * C + k];
                c0v = Wh[k * C + t];  c1v = Wh[k * C + t + 256];
            }
            a00 += r0v * c0v; a01 += r0v * c1v;
            a10 += r1v * c0v; a11 += r1v * c1v;
        }
        if (isA) {
            A[r0 * C + t] = a00;       A[r0 * C + t + 256] = a01;
            A[(r0 + 1) * C + t] = a10; A[(r0 + 1) * C + t + 256] = a11;
        } else {
            Wz16[FT_IDX(r0, t)] = (_Float16)a00;
            Wz16[FT_IDX(r0, t + 256)] = (_Float16)a01;
            Wz16[FT_IDX(r0 + 1, t)] = (_Float16)a10;
            Wz16[FT_IDX(r0 + 1, t + 256)] = (_Float16)a11;
        }
    } else if (bx < 520) {                       // betaf[b][co] = bf[co] - sum_i Wf[co][i]*mc*rc
        int g = (bx - 512) * 256 + t, b = g >> 9, co = g & 511;
        float acc = 0.f;
        for (int i = 0; i < C; i++) acc += Wf[co * C + i] * mc[b * C + i] * rc[b * C + i];
        betaf[g] = bf[co] - acc;
    } else {                                     // bz[co] = sum_i Wo[co][i]*bh[i]
        int co = (bx - 520) * 256 + t;
        float acc = 0.f;
        for (int i = 0; i < C; i++) acc += Wo[co * C + i] * bh[i];
        bz[co] = acc;
    }
}

// ---------------------------------------------------------------------------
// 2b) As[b] = diag(rc_b) * A * diag(rs_b), f16 FT layout (into dead SP buf).
// ---------------------------------------------------------------------------
__global__ void scaleA_kernel(char* __restrict__ ws)
{
    const float* __restrict__ A = (const float*)(ws + OFF_A);
    const float* __restrict__ rc = (const float*)(ws + OFF_RC);
    const float* __restrict__ rs = (const float*)(ws + OFF_RS);
    _Float16* __restrict__ As = (_Float16*)(ws + OFF_SP);

    int gid = blockIdx.x * 256 + threadIdx.x;   // 131072 = 4b * 512 sub * 64
    int b = gid >> 15, rem = gid & 32767;
    int sub = rem >> 6, low6 = rem & 63;
    int r16 = sub >> 4, cb4 = sub & 15;
    int q = low6 >> 4, l16 = low6 & 15;
    int r = r16 * 16 + l16, j0 = (cb4 * 4 + q) * 8;

    float4 a0 = *(const float4*)&A[r * C + j0];
    float4 a1 = *(const float4*)&A[r * C + j0 + 4];
    float4 s0 = *(const float4*)&rs[b * C + j0];
    float4 s1 = *(const float4*)&rs[b * C + j0 + 4];
    float rcv = rc[b * C + r];
    fp16x8 o;
    o[0] = (_Float16)(a0.x * rcv * s0.x); o[1] = (_Float16)(a0.y * rcv * s0.y);
    o[2] = (_Float16)(a0.z * rcv * s0.z); o[3] = (_Float16)(a0.w * rcv * s0.w);
    o[4] = (_Float16)(a1.x * rcv * s1.x); o[5] = (_Float16)(a1.y * rcv * s1.y);
    o[6] = (_Float16)(a1.z * rcv * s1.z); o[7] = (_Float16)(a1.w * rcv * s1.w);
    *(fp16x8*)&As[(size_t)b * 262144 + (size_t)sub * 512 + low6 * 8] = o;
}

// v[b][j] = rs[b][j] * sum_co betaf[b][co]*Wg[co][j]
__global__ void precompute_v_kernel(const float* __restrict__ Wg, char* __restrict__ ws)
{
    const float* betaf = (const float*)(ws + OFF_BETAF);
    const float* rs = (const float*)(ws + OFF_RS);
    float* v = (float*)(ws + OFF_V);
    int g = blockIdx.x * 32 + (threadIdx.x >> 3);   // 0..2047 output index
    int b = g >> 9, j = g & 511, cq = threadIdx.x & 7;
    float acc = 0.f;
    for (int co = cq * 64; co < cq * 64 + 64; co++) acc += betaf[b * C + co] * Wg[co * C + j];
    acc += __shfl_xor(acc, 1);
    acc += __shfl_xor(acc, 2);
    acc += __shfl_xor(acc, 4);
    if (cq == 0) v[g] = rs[b * C + j] * acc;
}

// ---------------------------------------------------------------------------
// 3) fused prep GEMM -> Kt (f16 FT) and Hp (f16 tiled). All loads wave-linear.
// ---------------------------------------------------------------------------
__global__ void __launch_bounds__(256) prep_gemm_kernel(char* __restrict__ ws)
{
    const _Float16* __restrict__ As = (const _Float16*)(ws + OFF_SP);
    const _Float16* __restrict__ Wz16 = (const _Float16*)(ws + OFF_WZ);
    const float* __restrict__ bz = (const float*)(ws + OFF_BZ);
    const _Float16* __restrict__ xsT = (const _Float16*)(ws + OFF_XST);
    _Float16* __restrict__ Kt = (_Float16*)(ws + OFF_KT);
    _Float16* __restrict__ Hp = (_Float16*)(ws + OFF_HM);

    int bx = blockIdx.x;                 // 1024 = 4b * 8 rowblk * 32 mblk
    int b = bx & 3, rest = bx >> 2;
    int r128 = rest >> 5, mb = rest & 31;
    int r0 = r128 * 128, m0 = mb * 128;
    int w = threadIdx.x >> 6, lane = threadIdx.x & 63, q = lane >> 4, l16 = lane & 15;
    int wr = (w & 1) * 64, wm = (w >> 1) * 64;
    bool isK = (r0 < 512);
    int rbase = (isK ? r0 : r0 - 512) + wr;

    f32x4 zz = {0.f, 0.f, 0.f, 0.f};
    f32x4 acc[4][4];
    #pragma unroll
    for (int rt = 0; rt < 4; rt++)
        #pragma unroll
        for (int mt = 0; mt < 4; mt++) acc[rt][mt] = zz;

    const _Float16* ap = (isK ? As + (size_t)b * 262144 : Wz16)
                         + (size_t)(rbase >> 4) * 8192 + q * 128 + l16 * 8;
    const _Float16* xb = xsT + (size_t)b * HW * C
                             + (size_t)((m0 + wm) >> 4) * 8192 + q * 128 + l16 * 8;

    for (int ks = 0; ks < 16; ks++) {
        fp16x8 afr[4], bfr[4];
        #pragma unroll
        for (int rt = 0; rt < 4; rt++)
            afr[rt] = *(const fp16x8*)(ap + (size_t)rt * 8192 + ks * 512);
        #pragma unroll
        for (int mt = 0; mt < 4; mt++)
            bfr[mt] = *(const fp16x8*)(xb + (size_t)(mt * 16 + ks) * 512);
        #pragma unroll
        for (int rt = 0; rt < 4; rt++)
            #pragma unroll
            for (int mt = 0; mt < 4; mt++)
                acc[rt][mt] = __builtin_amdgcn_mfma_f32_16x16x32_f16(afr[rt], bfr[mt], acc[rt][mt], 0, 0, 0);
    }

    if (isK) {
        _Float16* KtB = Kt + (size_t)b * HW * C;
        #pragma unroll
        for (int rt = 0; rt < 4; rt++)
            #pragma unroll
            for (int mt = 0; mt < 4; mt++) {
                int m = m0 + wm + mt * 16 + l16;
                int cb = r0 + wr + rt * 16 + q * 4;
                fp16x4 h;
                h[0] = (_Float16)acc[rt][mt][0]; h[1] = (_Float16)acc[rt][mt][1];
                h[2] = (_Float16)acc[rt][mt][2]; h[3] = (_Float16)acc[rt][mt][3];
                *(fp16x4*)&KtB[FT_IDX(m, cb)] = h;
            }
    } else {
        _Float16* HpB = Hp + (size_t)b * 2097152;
        #pragma unroll
        for (int rt = 0; rt < 4; rt++) {
            float bzv[4];
            #pragma unroll
            for (int reg = 0; reg < 4; reg++) bzv[reg] = bz[rbase + rt * 16 + q * 4 + reg];
            #pragma unroll
            for (int mt = 0; mt < 4; mt++) {
                int m = m0 + wm + mt * 16 + l16;
                int mbase = (m >> 3) * 128 + (m & 7);
                #pragma unroll
                for (int reg = 0; reg < 4; reg++) {
                    int co = rbase + rt * 16 + q * 4 + reg;
                    HpB[(size_t)(co >> 4) * 65536 + mbase + (co & 15) * 8] =
                        (_Float16)(acc[rt][mt][reg] + bzv[reg]);
                }
            }
        }
    }
}

// ---------------------------------------------------------------------------
// 4) t[b][m] = sum_j v[b][j] * xsT[b][m][j] — wave-linear FT loads.
// ---------------------------------------------------------------------------
__global__ void t_kernel(char* __restrict__ ws)
{
    const float* v = (const float*)(ws + OFF_V);
    const _Float16* __restrict__ xsT = (const _Float16*)(ws + OFF_XST);
    float* tG = (float*)(ws + OFF_T);
    int bx = blockIdx.x;                      // 256 = 4 b * 64 mblk(64m)
    int b = bx >> 6, mb = bx & 63;
    int tid = threadIdx.x, w = tid >> 6, lane = tid & 63, q = lane >> 4, l16 = lane & 15;
    int M16 = mb * 4 + w;                     // m-subtile; m = M16*16 + l16
    const _Float16* p = xsT + (size_t)b * HW * C + (size_t)M16 * 8192 + q * 128 + l16 * 8;
    const float* vp = v + b * C + q * 8;
    float acc = 0.f;
    #pragma unroll
    for (int st = 0; st < 16; st++) {
        fp16x8 xv = *(const fp16x8*)(p + st * 512);
        float4 v0 = *(const float4*)(vp + st * 32);
        float4 v1 = *(const float4*)(vp + st * 32 + 4);
        acc += (float)xv[0] * v0.x + (float)xv[1] * v0.y + (float)xv[2] * v0.z + (float)xv[3] * v0.w
             + (float)xv[4] * v1.x + (float)xv[5] * v1.y + (float)xv[6] * v1.z + (float)xv[7] * v1.w;
    }
    acc += __shfl_xor(acc, 16);
    acc += __shfl_xor(acc, 32);
    if (q == 0) tG[b * HW + M16 * 16 + l16] = acc;
}

// ---------------------------------------------------------------------------
// 5) pass A: S-tile = Q @ Kt^T (128x128, K=512) + t[m], LDS-STAGED:
//    both 8KB K-step slices staged once per block (reg->ds_write, dbuf,
//    one barrier/K-step — pv's proven pattern). Halves L2 traffic + TA
//    instrs; fragments become conflict-free ds_read_b128. Epilogue (max/
//    exp/sum, ML, S-store) identical; stage buffers union with Pl (36KB).
// ---------------------------------------------------------------------------
__global__ void __launch_bounds__(256, 4) qk_kernel(char* __restrict__ ws)
{
    const _Float16* __restrict__ xcT = (const _Float16*)(ws + OFF_XCT);
    const _Float16* __restrict__ Kt = (const _Float16*)(ws + OFF_KT);
    const float* __restrict__ tG = (const float*)(ws + OFF_T);
    float2* __restrict__ ML = (float2*)(ws + OFF_ML);
    _Float16* __restrict__ Sg = (_Float16*)(ws + OFF_S);

    int bx = blockIdx.x;                  // 4096: low3 = b*2+mhi (XCD-pinned)
    int b = (bx >> 1) & 3, mhi = bx & 1;
    int rest = bx >> 3, mlo = rest & 15, ntile = rest >> 4;
    int m0 = (mhi * 16 + mlo) * 128, n0 = ntile * 128;
    int tid = threadIdx.x, w = tid >> 6, lane = tid & 63, q = lane >> 4, l16 = lane & 15;
    int wn = (w & 1) * 64, wm = (w >> 1) * 64;

    __shared__ char lbuf[36864];          // loop: Ax[2][8KB]+Bx[2][8KB]; epilogue: Pl
    _Float16* Ax0 = (_Float16*)lbuf;                  // [2][4096]
    _Float16* Bx0 = (_Float16*)(lbuf + 16384);        // [2][4096]

    // staging geometry: slice = 8 subtiles x 1KB; thread covers 16 f16 (2x16B)
    int st = tid >> 5, so = (tid & 31) * 16;
    const _Float16* gA = xcT + (size_t)b * HW * C + ((size_t)(n0 >> 4) + st) * 8192 + so;
    const _Float16* gB = Kt + (size_t)b * HW * C + ((size_t)(m0 >> 4) + st) * 8192 + so;

    // prologue: stage ks=0 into buffer 0
    {
        fp16x8 a0 = *(const fp16x8*)(gA);
        fp16x8 a1 = *(const fp16x8*)(gA + 8);
        fp16x8 b0 = *(const fp16x8*)(gB);
        fp16x8 b1 = *(const fp16x8*)(gB + 8);
        *(fp16x8*)&Ax0[tid * 16] = a0; *(fp16x8*)&Ax0[tid * 16 + 8] = a1;
        *(fp16x8*)&Bx0[tid * 16] = b0; *(fp16x8*)&Bx0[tid * 16 + 8] = b1;
    }
    __syncthreads();

    f32x4 zz = {0.f, 0.f, 0.f, 0.f};
    f32x4 acc[4][4];
    #pragma unroll
    for (int nt = 0; nt < 4; nt++)
        #pragma unroll
        for (int mt = 0; mt < 4; mt++) acc[nt][mt] = zz;

    int aoff = ((wn >> 4)) * 512 + q * 128 + l16 * 8;
    int boff = ((wm >> 4)) * 512 + q * 128 + l16 * 8;

    for (int ks = 0; ks < 16; ks++) {
        int buf = ks & 1;
        _Float16* Axc = Ax0 + buf * 4096;
        _Float16* Bxc = Bx0 + buf * 4096;
        // issue next slice's global loads early (latency hides under MFMA)
        fp16x8 a0n, a1n, b0n, b1n;
        if (ks < 15) {
            a0n = *(const fp16x8*)(gA + (ks + 1) * 512);
            a1n = *(const fp16x8*)(gA + (ks + 1) * 512 + 8);
            b0n = *(const fp16x8*)(gB + (ks + 1) * 512);
            b1n = *(const fp16x8*)(gB + (ks + 1) * 512 + 8);
        }

        fp16x8 afr[4], bfr[4];
        #pragma unroll
        for (int nt = 0; nt < 4; nt++)
            afr[nt] = *(const fp16x8*)&Axc[aoff + nt * 512];
        #pragma unroll
        for (int mt = 0; mt < 4; mt++)
            bfr[mt] = *(const fp16x8*)&Bxc[boff + mt * 512];
        #pragma unroll
        for (int nt = 0; nt < 4; nt++)
            #pragma unroll
            for (int mt = 0; mt < 4; mt++)
                acc[nt][mt] = __builtin_amdgcn_mfma_f32_16x16x32_f16(afr[nt], bfr[mt], acc[nt][mt], 0, 0, 0);

        if (ks < 15) {
            _Float16* Axn = Ax0 + (buf ^ 1) * 4096;
            _Float16* Bxn = Bx0 + (buf ^ 1) * 4096;
            *(fp16x8*)&Axn[tid * 16] = a0n; *(fp16x8*)&Axn[tid * 16 + 8] = a1n;
            *(fp16x8*)&Bxn[tid * 16] = b0n; *(fp16x8*)&Bxn[tid * 16 + 8] = b1n;
        }
        __syncthreads();
    }

    // ---- epilogue: + t[m], per-row tile max / exp / sum ----
    float tv[4];
    #pragma unroll
    for (int mt = 0; mt < 4; mt++) tv[mt] = tG[b * HW + m0 + wm + mt * 16 + l16];
    #pragma unroll
    for (int nt = 0; nt < 4; nt++)
        #pragma unroll
        for (int mt = 0; mt < 4; mt++)
            #pragma unroll
            for (int reg = 0; reg < 4; reg++) acc[nt][mt][reg] += tv[mt];

    float rm[4][4], sum[4][4];
    #pragma unroll
    for (int nt = 0; nt < 4; nt++)
        #pragma unroll
        for (int reg = 0; reg < 4; reg++)
            rm[nt][reg] = fmaxf(fmaxf(acc[nt][0][reg], acc[nt][1][reg]),
                                fmaxf(acc[nt][2][reg], acc[nt][3][reg]));
    #pragma unroll
    for (int s = 1; s < 16; s <<= 1)
        #pragma unroll
        for (int nt = 0; nt < 4; nt++)
            #pragma unroll
            for (int reg = 0; reg < 4; reg++)
                rm[nt][reg] = fmaxf(rm[nt][reg], __shfl_xor(rm[nt][reg], s));
    #pragma unroll
    for (int nt = 0; nt < 4; nt++)
        #pragma unroll
        for (int reg = 0; reg < 4; reg++) sum[nt][reg] = 0.f;
    #pragma unroll
    for (int nt = 0; nt < 4; nt++)
        #pragma unroll
        for (int mt = 0; mt < 4; mt++)
            #pragma unroll
            for (int reg = 0; reg < 4; reg++) {
                float pv = __expf(acc[nt][mt][reg] - rm[nt][reg]);
                acc[nt][mt][reg] = pv;
                sum[nt][reg] += pv;
            }
    #pragma unroll
    for (int s = 1; s < 16; s <<= 1)
        #pragma unroll
        for (int nt = 0; nt < 4; nt++)
            #pragma unroll
            for (int reg = 0; reg < 4; reg++)
                sum[nt][reg] += __shfl_xor(sum[nt][reg], s);

    int tl = (m0 + wm) >> 6;
    if (l16 == 0) {
        #pragma unroll
        for (int nt = 0; nt < 4; nt++)
            #pragma unroll
            for (int reg = 0; reg < 4; reg++)
                ML[((size_t)(b * HW + n0 + wn + nt * 16 + q * 4 + reg)) * 64 + tl] =
                    make_float2(rm[nt][reg], sum[nt][reg]);
    }

    // ---- f16 + LDS transpose-spill (Pl unions lbuf), then 16B stores ----
    _Float16 (*Pl)[64][72] = (_Float16(*)[64][72])lbuf;
    #pragma unroll
    for (int nt = 0; nt < 4; nt++)
        #pragma unroll
        for (int mt = 0; mt < 4; mt++)
            #pragma unroll
            for (int reg = 0; reg < 4; reg++)
                Pl[w][nt * 16 + q * 4 + reg][mt * 16 + l16] = (_Float16)acc[nt][mt][reg];
    __syncthreads();
    _Float16* SgB = Sg + (size_t)b * 16777216;
    #pragma unroll
    for (int i = 0; i < 8; i++) {
        int row = i * 8 + (lane >> 3), c8 = (lane & 7) * 8;
        int n = n0 + wn + row, m = m0 + wm + c8;
        *(fp16x8*)&SgB[SFT_IDX(n, m)] = *(const fp16x8*)&Pl[w][row][c8];
    }
}

// ---------------------------------------------------------------------------
// 5b) per-row global softmax scales: Scl[b][tile][n] = e^(m_tile - M)/L (f32)
// ---------------------------------------------------------------------------
__global__ void __launch_bounds__(256) scale_kernel(char* __restrict__ ws)
{
    const float* __restrict__ mlf0 = (const float*)(ws + OFF_ML);
    float* __restrict__ Scl = (float*)(ws + OFF_XCT);
    __shared__ float mlv[64][129];       // [row][2*tile + {0:max,1:sum}]
    __shared__ float Ms[64], Li[64];

    int g0 = blockIdx.x * 64;            // global row base (b*4096 + n), 16384 total
    int tid = threadIdx.x;
    const float* mlf = mlf0 + (size_t)g0 * 128;   // 64 rows x 128 f32 (float2[64])

    #pragma unroll
    for (int i = 0; i < 8; i++) {
        int f4 = i * 256 + tid;          // 2048 float4 = 64 rows x 32
        int row = f4 >> 5, c4 = (f4 & 31) * 4;
        float4 v = *(const float4*)(mlf + row * 128 + c4);
        mlv[row][c4] = v.x; mlv[row][c4 + 1] = v.y;
        mlv[row][c4 + 2] = v.z; mlv[row][c4 + 3] = v.w;
    }
    __syncthreads();
    if (tid < 64) {
        float M = -1e30f;
        #pragma unroll
        for (int k = 0; k < 64; k++) M = fmaxf(M, mlv[tid][k * 2]);
        float L = 0.f;
        #pragma unroll
        for (int k = 0; k < 64; k++) L += mlv[tid][k * 2 + 1] * __expf(mlv[tid][k * 2] - M);
        Ms[tid] = M; Li[tid] = 1.f / L;
    }
    __syncthreads();
    int b = g0 >> 12, nbase = g0 & 4095;
    float* sp = Scl + (size_t)b * 262144 + nbase;
    int row = tid & 63, tsub = tid >> 6;
    #pragma unroll
    for (int pass = 0; pass < 16; pass++) {
        int tile = pass * 4 + tsub;
        sp[(size_t)tile * 4096 + row] = __expf(mlv[row][tile * 2] - Ms[row]) * Li[row];
    }
}

// ---------------------------------------------------------------------------
// 6) pass C: O = (p * scale) @ Hp^T — LDS-Hp pipeline (unchanged from r6).
// ---------------------------------------------------------------------------
__global__ void __launch_bounds__(256, 4) pv_kernel(const float* __restrict__ xc,
                                                    const float* __restrict__ bo,
                                                    float* __restrict__ out,
                                                    char* __restrict__ ws)
{
    const _Float16* __restrict__ Sft = (const _Float16*)(ws + OFF_S);
    const _Float16* __restrict__ Hp = (const _Float16*)(ws + OFF_HM);
    const float* __restrict__ Scl = (const float*)(ws + OFF_XCT);

    int bx = blockIdx.x;                 // 1024 = 32 ntb * 8 cog * 4 b
    int b = bx & 3, cog = (bx >> 2) & 7, ntb = bx >> 5;
    int co0 = cog * 64;
    int tid = threadIdx.x, w = tid >> 6, lane = tid & 63, q = lane >> 4, l16 = lane & 15;
    int n0w = ntb * 128 + w * 32;

    __shared__ _Float16 Hl[2][4096];     // 8KB chunk slice (64co x 64keys), dbuf

    int ln64 = lane;
    const _Float16* hsrc = Hp + (size_t)b * 2097152
                              + (size_t)((co0 >> 4) + w) * 65536 + ln64 * 8;
    const _Float16* sb = Sft + (size_t)b * 16777216
                             + (size_t)(ntb * 8 + w * 2) * 65536 + q * 128 + l16 * 8;
    const float* sc = Scl + (size_t)b * 262144 + n0w + q * 4;

    // prologue: stage chunk 0
    {
        fp16x8 s0 = *(const fp16x8*)(hsrc);
        fp16x8 s1 = *(const fp16x8*)(hsrc + 512);
        *(fp16x8*)&Hl[0][w * 1024 + ln64 * 8] = s0;
        *(fp16x8*)&Hl[0][w * 1024 + 512 + ln64 * 8] = s1;
    }
    __syncthreads();

    f32x4 zz = {0.f, 0.f, 0.f, 0.f};
    f32x4 acc[2][4];
    #pragma unroll
    for (int nt = 0; nt < 2; nt++)
        #pragma unroll
        for (int ct = 0; ct < 4; ct++) acc[nt][ct] = zz;

    for (int chunk = 0; chunk < 64; chunk++) {
        int buf = chunk & 1;
        fp16x8 s0n, s1n;
        if (chunk < 63) {
            s0n = *(const fp16x8*)(hsrc + (chunk + 1) * 1024);
            s1n = *(const fp16x8*)(hsrc + (chunk + 1) * 1024 + 512);
        }

        f32x4 tmp[2][4];
        #pragma unroll
        for (int km = 0; km < 2; km++) {
            fp16x8 afr[2], bfr[4];
            #pragma unroll
            for (int nt = 0; nt < 2; nt++)
                afr[nt] = *(const fp16x8*)(sb + (size_t)nt * 65536 + (chunk * 2 + km) * 512);
            #pragma unroll
            for (int ct = 0; ct < 4; ct++)
                bfr[ct] = *(const fp16x8*)&Hl[buf][ct * 1024 + (km * 4 + q) * 128 + l16 * 8];
            #pragma unroll
            for (int nt = 0; nt < 2; nt++)
                #pragma unroll
                for (int ct = 0; ct < 4; ct++)
                    tmp[nt][ct] = __builtin_amdgcn_mfma_f32_16x16x32_f16(
                        afr[nt], bfr[ct], km == 0 ? zz : tmp[nt][ct], 0, 0, 0);
        }
        float4 sv0 = *(const float4*)(sc + chunk * 4096);
        float4 sv1 = *(const float4*)(sc + chunk * 4096 + 16);
        float sva[2][4] = {{sv0.x, sv0.y, sv0.z, sv0.w}, {sv1.x, sv1.y, sv1.z, sv1.w}};
        #pragma unroll
        for (int nt = 0; nt < 2; nt++)
            #pragma unroll
            for (int ct = 0; ct < 4; ct++)
                #pragma unroll
                for (int reg = 0; reg < 4; reg++)
                    acc[nt][ct][reg] += tmp[nt][ct][reg] * sva[nt][reg];

        if (chunk < 63) {
            *(fp16x8*)&Hl[buf ^ 1][w * 1024 + ln64 * 8] = s0n;
            *(fp16x8*)&Hl[buf ^ 1][w * 1024 + 512 + ln64 * 8] = s1n;
        }
        __syncthreads();
    }

    // ---- epilogue: + bo + content ----
    #pragma unroll
    for (int nt = 0; nt < 2; nt++)
        #pragma unroll
        for (int ct = 0; ct < 4; ct++) {
            int co = co0 + ct * 16 + l16;
            size_t base = ((size_t)(b * C + co)) * HW + n0w + nt * 16 + q * 4;
            float4 cv = *(const float4*)&xc[base];
            float bov = bo[co];
            float4 o;
            o.x = acc[nt][ct][0] + bov + cv.x;
            o.y = acc[nt][ct][1] + bov + cv.y;
            o.z = acc[nt][ct][2] + bov + cv.z;
            o.w = acc[nt][ct][3] + bov + cv.w;
            *(float4*)&out[base] = o;
        }
}

// ---------------------------------------------------------------------------
extern "C" void kernel_launch(void* const* d_in, const int* in_sizes, int n_in,
                              void* d_out, int out_size, void* d_ws, size_t ws_size,
                              hipStream_t stream)
{
    const float* content = (const float*)d_in[0];
    const float* style   = (const float*)d_in[1];
    const float* Wf = (const float*)d_in[2];
    const float* bf = (const float*)d_in[3];
    const float* Wg = (const float*)d_in[4];
    // d_in[5] = bg: provably unused (softmax row-constant)
    const float* Wh = (const float*)d_in[6];
    const float* bh = (const float*)d_in[7];
    const float* Wo = (const float*)d_in[8];
    const float* bo = (const float*)d_in[9];
    float* out = (float*)d_out;
    char* ws = (char*)d_ws;

    transpose_stats_kernel<<<4096, 256, 0, stream>>>(content, style, ws);
    finalize_stats_kernel<<<16, 256, 0, stream>>>(ws);
    precompute_kernel<<<522, 256, 0, stream>>>(Wf, Wg, Wo, Wh, bf, bh, ws);
    scaleA_kernel<<<512, 256, 0, stream>>>(ws);
    precompute_v_kernel<<<64, 256, 0, stream>>>(Wg, ws);
    prep_gemm_kernel<<<1024, 256, 0, stream>>>(ws);
    t_kernel<<<256, 256, 0, stream>>>(ws);
    qk_kernel<<<4096, 256, 0, stream>>>(ws);
    scale_kernel<<<256, 256, 0, stream>>>(ws);
    pv_kernel<<<1024, 256, 0, stream>>>(content, bo, out, ws);
}